// Round 2
// baseline (2838.824 us; speedup 1.0000x reference)
//
#include <hip/hip_runtime.h>
#include <stdint.h>

#define BB 64
#define TT 512
#define DD 256
#define HH 512
#define NG 2048
#define BT (BB*TT)
#define NCLS 1000
#define MAXS 8

typedef _Float16 f16;
typedef _Float16 f16x2 __attribute__((ext_vector_type(2)));
typedef _Float16 f16x4 __attribute__((ext_vector_type(4)));
typedef _Float16 f16x8 __attribute__((ext_vector_type(8)));
typedef float f32x4 __attribute__((ext_vector_type(4)));

// bucket list offsets: OFF[s] = 64 * sum_{s'<s} ceil(512/(s'+1)), s=0..7; total 89216
__device__ const int d_OFF[MAXS] = {0,32768,49152,60096,68288,74880,80384,85120};

__device__ __forceinline__ float sigf(float x) { return 1.0f / (1.0f + __expf(-x)); }
__device__ __forceinline__ float tanh_(float x) {
  float e = __expf(-2.0f * fabsf(x));
  float r = (1.0f - e) / (1.0f + e);
  return copysignf(r, x);
}
__device__ __forceinline__ f32x4 mfma16(f16x8 a, f16x8 b, f32x4 c) {
  return __builtin_amdgcn_mfma_f32_16x16x32_f16(a, b, c, 0, 0, 0);
}
__device__ __forceinline__ void gload16(const void* g, void* l) {
  __builtin_amdgcn_global_load_lds((const __attribute__((address_space(1))) void*)g,
                                   (__attribute__((address_space(3))) void*)l, 16, 0, 0);
}

// device-scope grid barrier: release-fence, arrive, relaxed spin, acquire-fence
__device__ __forceinline__ void gbar(int* ctr, int phase, int nblk) {
  __syncthreads();
  if (threadIdx.x == 0) {
    __threadfence();  // release: write back this XCD's dirty L2 lines
    __hip_atomic_fetch_add(ctr + phase, 1, __ATOMIC_RELAXED, __HIP_MEMORY_SCOPE_AGENT);
    while (__hip_atomic_load(ctr + phase, __ATOMIC_RELAXED, __HIP_MEMORY_SCOPE_AGENT) < nblk) {
      __builtin_amdgcn_s_sleep(8);
    }
    __threadfence();  // acquire: invalidate stale L1/L2 lines
  }
  __syncthreads();
}

// ---------------- generic f32 -> f16 cast (vectorized) ----------------
__global__ __launch_bounds__(256) void cast_f16(const float* __restrict__ s, f16* __restrict__ d, int n4) {
  int i = blockIdx.x * 256 + threadIdx.x;
  int stride = gridDim.x * 256;
  for (; i < n4; i += stride) {
    float4 v = ((const float4*)s)[i];
    f16x4 o = { (f16)v.x, (f16)v.y, (f16)v.z, (f16)v.w };
    ((f16x4*)d)[i] = o;
  }
}

__global__ __launch_bounds__(256) void bias_add(const float* __restrict__ a, const float* __restrict__ b,
                                                float* __restrict__ o, int n) {
  int i = blockIdx.x * 256 + threadIdx.x;
  if (i < n) o[i] = a[i] + b[i];
}

// ---------------- segment bucket lists (shared by both layers; same mask) ----------------
__global__ __launch_bounds__(512) void build_lists(const float* __restrict__ mask,
    int* __restrict__ counts, int* __restrict__ lists,
    int* __restrict__ tailcnt, int* __restrict__ taillist) {
  int b = blockIdx.x, t = threadIdx.x;
  __shared__ float sm[512];
  sm[t] = mask[b*TT + t];
  __syncthreads();
  int run = 0;
  for (int j = 1; j <= MAXS; ++j) {
    if (t - j < 0) break;
    if (sm[t - j] != 0.0f) run++; else break;
  }
  bool tail = (run >= MAXS);
  if (!tail) {
    int slot = atomicAdd(&counts[run], 1);
    lists[d_OFF[run] + slot] = b*TT + t;
  }
  // ordered (by t) per-batch list of tail positions via block scan
  unsigned long long bal = __ballot(tail);
  int lane = t & 63, w = t >> 6;
  int wpre = __popcll(bal & ((1ull << lane) - 1ull));
  __shared__ int wsum[8];
  if (lane == 0) wsum[w] = __popcll(bal);
  __syncthreads();
  int base = 0;
  for (int i = 0; i < w; ++i) base += wsum[i];
  if (tail) taillist[b*TT + base + wpre] = t;
  if (t == 0) {
    int tot = 0;
    for (int i = 0; i < 8; ++i) tot += wsum[i];
    tailcnt[b] = tot;
  }
}

// ---------------- projection GEMM: C[M][2048] = A[M][K] @ W[2048][K]^T + bias ----------------
// m97 structure: global_load_lds w16 (pre-swizzled source, swizzle-on-read), 128x128 tile,
// BK=64, 4 waves, XCD-chunked swizzle, LDS-restaged vectorized epilogue.
__global__ __launch_bounds__(256) void proj_gemm(const f16* __restrict__ A,
    const f16* __restrict__ W, const float* __restrict__ bias,
    f16* __restrict__ C, int K) {
  __shared__ __align__(16) f16 smem[128*128];   // As=[0,128*64), Bs=[128*64,..); epilogue uses all
  f16* As = smem;
  f16* Bs = smem + 128*64;
  const int nwg = gridDim.x;
  const int cpx = nwg >> 3;                      // blocks per XCD chunk
  const int b0i = blockIdx.x;
  const int swz = (b0i & 7) * cpx + (b0i >> 3);  // XCD gets contiguous chunk
  const int m0 = (swz >> 4) * 128;               // 16 n-panels -> m contiguous per XCD
  const int n0 = (swz & 15) * 128;
  const int tid = threadIdx.x;
  const int lane = tid & 63;
  const int w = tid >> 6;
  const int srg = lane >> 3;                     // row within 8-row group
  const int scol = lane & 7;                     // 16B chunk slot
  f32x4 acc[4][4] = {};
  for (int k0 = 0; k0 < K; k0 += 64) {
#pragma unroll
    for (int i = 0; i < 4; ++i) {
      int r0 = (i*4 + w) * 8;                    // wave-uniform 8-row group
      int row = r0 + srg;
      int cg = scol ^ (row & 7);                 // pre-swizzled global chunk
      gload16(A + (size_t)(m0 + row)*K + k0 + cg*8, As + r0*64);
      gload16(W + (size_t)(n0 + row)*K + k0 + cg*8, Bs + r0*64);
    }
    __syncthreads();                             // drains vmcnt(0) -> LDS ready
    {
      const int wm = (w >> 1) * 64;
      const int wn = (w & 1) * 64;
      const int cl = lane & 15;
      const int kq = lane >> 4;
#pragma unroll
      for (int ks = 0; ks < 2; ++ks) {
        int kc = ks*4 + kq;
        f16x8 af[4], bf[4];
#pragma unroll
        for (int mi = 0; mi < 4; ++mi) {
          int row = wm + mi*16 + cl;
          af[mi] = *(const f16x8*)(As + row*64 + ((kc ^ (row & 7)) * 8));
        }
#pragma unroll
        for (int ni = 0; ni < 4; ++ni) {
          int row = wn + ni*16 + cl;
          bf[ni] = *(const f16x8*)(Bs + row*64 + ((kc ^ (row & 7)) * 8));
        }
#pragma unroll
        for (int mi = 0; mi < 4; ++mi)
#pragma unroll
          for (int ni = 0; ni < 4; ++ni)
            acc[mi][ni] = mfma16(af[mi], bf[ni], acc[mi][ni]);
      }
    }
    __syncthreads();                             // reads done before next stage
  }
  // epilogue: stage f16 tile in LDS, then full-line vector stores
  {
    const int wm = (w >> 1) * 64;
    const int wn = (w & 1) * 64;
    const int cl = lane & 15;
    const int rq = lane >> 4;
#pragma unroll
    for (int ni = 0; ni < 4; ++ni) {
      int col = wn + ni*16 + cl;
      float bb = bias[n0 + col];
#pragma unroll
      for (int mi = 0; mi < 4; ++mi)
#pragma unroll
        for (int r = 0; r < 4; ++r)
          smem[(wm + mi*16 + rq*4 + r)*128 + col] = (f16)(acc[mi][ni][r] + bb);
    }
  }
  __syncthreads();
#pragma unroll
  for (int p = 0; p < 8; ++p) {
    int row = p*16 + (tid >> 4);
    int ch = tid & 15;
    f16x8 v = *(const f16x8*)(smem + row*128 + ch*8);
    *(f16x8*)(C + (size_t)(m0 + row)*NG + n0 + ch*8) = v;
  }
}

// ---------------- persistent LSTM: bucket0, buckets1..7, tail, [relu+LN] ----------------
__global__ __launch_bounds__(512, 4) void lstm_persist(
    const f16* __restrict__ Wh, const f16* __restrict__ G,
    f16* __restrict__ HS, f16* __restrict__ CS,
    const float* __restrict__ mask,
    const int* __restrict__ counts, const int* __restrict__ lists,
    const int* __restrict__ tailcnt, const int* __restrict__ taillist,
    int* ctr, const float* __restrict__ g, const float* __restrict__ be,
    f16* __restrict__ HOUT, int doLN) {
  const int nblk = gridDim.x;
  const int bid = blockIdx.x;
  const int tid = threadIdx.x;
  const int lane = tid & 63;
  const int w = tid >> 6;
  __shared__ int ridx[32];
  __shared__ float rmk[32];
  __shared__ __align__(4) f16 hsh[HH];
  __shared__ float gsh[NG];
  int ph = 0;

  // ---- phase: bucket 0 (h_prev = c_prev = 0) ----
  {
    int cnt = counts[0];
    for (int i = bid; i < cnt; i += nblk) {
      int row = lists[i];
      size_t gb = (size_t)row * NG;
      float gi = (float)G[gb + tid];
      float gg = (float)G[gb + 1024 + tid];
      float go = (float)G[gb + 1536 + tid];
      float m = mask[row];
      float c = sigf(gi) * tanh_(gg);
      float h = sigf(go) * tanh_(c);
      HS[(size_t)row*HH + tid] = (f16)(h*m);
      CS[(size_t)row*HH + tid] = (f16)(c*m);
    }
  }
  gbar(ctr, ph++, nblk);

  // ---- phases: buckets 1..7 (gathered-row MFMA) ----
  for (int s = 1; s < MAXS; ++s) {
    const int cnt = counts[s];
    const int* lst = lists + d_OFF[s];
    const int units = ((cnt + 31) >> 5) << 2;    // 32-row chunks x 4 j-quadrants
    for (int u = bid; u < units; u += nblk) {
      const int mbase = (u >> 2) * 32;
      const int jt = (u & 3) * 128 + w * 16;
      if (tid < 32) {
        int i = mbase + tid;
        int r = (i < cnt) ? lst[i] : -1;
        ridx[tid] = r;
        rmk[tid] = (r >= 0) ? mask[r] : 0.0f;
      }
      __syncthreads();
      const int cl = lane & 15, kq = lane >> 4;
      int am0 = ridx[cl], am1 = ridx[16 + cl];
      const f16* a0p = HS + (size_t)((am0 > 0) ? (am0 - 1) : 0)*HH + kq*8;
      const f16* a1p = HS + (size_t)((am1 > 0) ? (am1 - 1) : 0)*HH + kq*8;
      const f16* b0p = Wh + (size_t)(jt + cl)*HH + kq*8;
      const f16* b1p = b0p + (size_t)512*HH;
      const f16* b2p = b0p + (size_t)1024*HH;
      const f16* b3p = b0p + (size_t)1536*HH;
      f32x4 acc[2][4] = {};
#pragma unroll 4
      for (int ks = 0; ks < 16; ++ks) {
        f16x8 a0 = *(const f16x8*)(a0p + ks*32);
        f16x8 a1 = *(const f16x8*)(a1p + ks*32);
        f16x8 b0 = *(const f16x8*)(b0p + ks*32);
        f16x8 b1 = *(const f16x8*)(b1p + ks*32);
        f16x8 b2 = *(const f16x8*)(b2p + ks*32);
        f16x8 b3 = *(const f16x8*)(b3p + ks*32);
        acc[0][0] = mfma16(a0, b0, acc[0][0]);
        acc[1][0] = mfma16(a1, b0, acc[1][0]);
        acc[0][1] = mfma16(a0, b1, acc[0][1]);
        acc[1][1] = mfma16(a1, b1, acc[1][1]);
        acc[0][2] = mfma16(a0, b2, acc[0][2]);
        acc[1][2] = mfma16(a1, b2, acc[1][2]);
        acc[0][3] = mfma16(a0, b3, acc[0][3]);
        acc[1][3] = mfma16(a1, b3, acc[1][3]);
      }
      const int j = jt + cl;
#pragma unroll
      for (int mi = 0; mi < 2; ++mi)
#pragma unroll
        for (int r = 0; r < 4; ++r) {
          int slot = mi*16 + kq*4 + r;
          int row = ridx[slot];
          if (row >= 0) {
            size_t gb = (size_t)row * NG;
            float gi = acc[mi][0][r] + (float)G[gb + j];
            float gf = acc[mi][1][r] + (float)G[gb + 512 + j];
            float gg = acc[mi][2][r] + (float)G[gb + 1024 + j];
            float go = acc[mi][3][r] + (float)G[gb + 1536 + j];
            float cp = (float)CS[(size_t)(row - 1)*HH + j];
            float c = sigf(gf)*cp + sigf(gi)*tanh_(gg);
            float h = sigf(go)*tanh_(c);
            float m = rmk[slot];
            HS[(size_t)row*HH + j] = (f16)(h*m);
            CS[(size_t)row*HH + j] = (f16)(c*m);
          }
        }
      __syncthreads();                           // protect ridx/rmk reuse
    }
    gbar(ctr, ph++, nblk);
  }

  // ---- phase: tail (run >= 8), sequential per batch ----
  if (bid < BB) {
    int n = tailcnt[bid];
    for (int i = 0; i < n; ++i) {
      int t = taillist[bid*TT + i];
      size_t row = (size_t)bid*TT + t;
      if (tid < 256)
        ((uint32_t*)hsh)[tid] = ((const uint32_t*)(HS + (row - 1)*HH))[tid];
      __syncthreads();
#pragma unroll
      for (int rep = 0; rep < 4; ++rep) {
        int o = tid + rep*512;
        float a = (float)G[row*NG + o];
        const f16x8* wr = (const f16x8*)(Wh + (size_t)o*HH);
        const f16x2* hp = (const f16x2*)hsh;
#pragma unroll 4
        for (int k8 = 0; k8 < 64; ++k8) {
          f16x8 wv = wr[k8];
          f16x2 p0 = {wv[0], wv[1]}, p1 = {wv[2], wv[3]}, p2 = {wv[4], wv[5]}, p3 = {wv[6], wv[7]};
          a = __builtin_amdgcn_fdot2(p0, hp[k8*4+0], a, false);
          a = __builtin_amdgcn_fdot2(p1, hp[k8*4+1], a, false);
          a = __builtin_amdgcn_fdot2(p2, hp[k8*4+2], a, false);
          a = __builtin_amdgcn_fdot2(p3, hp[k8*4+3], a, false);
        }
        gsh[o] = a;
      }
      __syncthreads();
      {
        float cp = (float)CS[(row - 1)*HH + tid];
        float c = sigf(gsh[512 + tid])*cp + sigf(gsh[tid])*tanh_(gsh[1024 + tid]);
        float h = sigf(gsh[1536 + tid])*tanh_(c);
        float m = mask[row];
        HS[row*HH + tid] = (f16)(h*m);
        CS[row*HH + tid] = (f16)(c*m);
      }
      __syncthreads();
    }
  }
  gbar(ctr, ph++, nblk);

  // ---- phase: relu + layernorm (layer0 only), wave-per-row ----
  if (doLN) {
    float gv[8], bv[8];
#pragma unroll
    for (int e = 0; e < 8; ++e) { gv[e] = g[lane*8 + e]; bv[e] = be[lane*8 + e]; }
    int nw = nblk * 8;
    for (int row = bid*8 + w; row < BT; row += nw) {
      f16x8 hv = *(const f16x8*)(HS + (size_t)row*HH + lane*8);
      float xv[8]; float s1 = 0.f, s2 = 0.f;
#pragma unroll
      for (int e = 0; e < 8; ++e) { float x = fmaxf((float)hv[e], 0.f); xv[e] = x; s1 += x; s2 += x*x; }
#pragma unroll
      for (int o = 1; o < 64; o <<= 1) { s1 += __shfl_xor(s1, o); s2 += __shfl_xor(s2, o); }
      float mu = s1 * (1.0f/512.0f);
      float var = s2 * (1.0f/512.0f) - mu*mu;
      float rs = rsqrtf(var + 1e-5f);
      f16x8 ov;
#pragma unroll
      for (int e = 0; e < 8; ++e) ov[e] = (f16)((xv[e] - mu)*rs*gv[e] + bv[e]);
      *(f16x8*)(HOUT + (size_t)row*HH + lane*8) = ov;
    }
  }
}

// layernorm of the final (t=T-1) hidden state, f32 output
__global__ __launch_bounds__(512) void ln_last(const f16* __restrict__ HS,
    const float* __restrict__ g, const float* __restrict__ be, float* __restrict__ out) {
  int b = blockIdx.x;
  int j = threadIdx.x;
  float x = fmaxf((float)HS[((size_t)b*TT + (TT-1))*HH + j], 0.0f);
  float s1 = x, s2 = x*x;
  for (int o = 32; o > 0; o >>= 1) { s1 += __shfl_down(s1, o); s2 += __shfl_down(s2, o); }
  __shared__ float a1[8], a2[8];
  int w = j >> 6;
  if ((j & 63) == 0) { a1[w] = s1; a2[w] = s2; }
  __syncthreads();
  if (j == 0) {
    float t1 = 0.f, t2 = 0.f;
    for (int i = 0; i < 8; ++i) { t1 += a1[i]; t2 += a2[i]; }
    a1[0] = t1; a2[0] = t2;
  }
  __syncthreads();
  float mu = a1[0] * (1.0f/512.0f);
  float var = a2[0] * (1.0f/512.0f) - mu*mu;
  float y = (x - mu) * rsqrtf(var + 1e-5f) * g[j] + be[j];
  out[b*HH + j] = y;
}

// ---------------- final classifier: out[64][1000] = hf @ fcW^T + fcb ----------------
__global__ __launch_bounds__(256) void fc_kernel(const float* __restrict__ hf,
    const float* __restrict__ W, const float* __restrict__ bias, float* __restrict__ out) {
  int b = blockIdx.y;
  int c = blockIdx.x * 256 + threadIdx.x;
  __shared__ float hsh[512];
  hsh[threadIdx.x] = hf[b*HH + threadIdx.x];
  hsh[threadIdx.x + 256] = hf[b*HH + 256 + threadIdx.x];
  __syncthreads();
  if (c < NCLS) {
    const float4* wr = (const float4*)(W + (size_t)c*HH);
    float acc = bias[c];
#pragma unroll 4
    for (int k4 = 0; k4 < 128; ++k4) {
      float4 wv = wr[k4];
      acc += wv.x*hsh[k4*4] + wv.y*hsh[k4*4+1] + wv.z*hsh[k4*4+2] + wv.w*hsh[k4*4+3];
    }
    out[b*NCLS + c] = acc;
  }
}

extern "C" void kernel_launch(void* const* d_in, const int* in_sizes, int n_in,
                              void* d_out, int out_size, void* d_ws, size_t ws_size,
                              hipStream_t stream) {
  (void)in_sizes; (void)n_in; (void)out_size;
  const float* x    = (const float*)d_in[0];
  const float* mask = (const float*)d_in[1];
  const float* Wih0 = (const float*)d_in[2];
  const float* Whh0 = (const float*)d_in[3];
  const float* bih0 = (const float*)d_in[4];
  const float* bhh0 = (const float*)d_in[5];
  const float* g0   = (const float*)d_in[6];
  const float* be0  = (const float*)d_in[7];
  const float* Wih1 = (const float*)d_in[8];
  const float* Whh1 = (const float*)d_in[9];
  const float* bih1 = (const float*)d_in[10];
  const float* bhh1 = (const float*)d_in[11];
  const float* g1   = (const float*)d_in[12];
  const float* be1  = (const float*)d_in[13];
  const float* fcW  = (const float*)d_in[14];
  const float* fcb  = (const float*)d_in[15];
  float* out = (float*)d_out;

  char* ws = (char*)d_ws;
  size_t off = 0;
  auto alloc = [&](size_t bytes) { size_t o = off; off += (bytes + 255) & ~(size_t)255; return o; };
  f16* G      = (f16*)(ws + alloc((size_t)BT*NG*2));      // 128MB, reused both layers
  f16* HS     = (f16*)(ws + alloc((size_t)BT*HH*2));      // 32MB
  f16* CS     = (f16*)(ws + alloc((size_t)BT*HH*2));      // 32MB
  f16* H0LN   = (f16*)(ws + alloc((size_t)BT*HH*2));      // 32MB; first x-f16, later LN(layer0)
  f16* W16ih0 = (f16*)(ws + alloc((size_t)NG*DD*2));
  f16* W16hh0 = (f16*)(ws + alloc((size_t)NG*HH*2));
  f16* W16ih1 = (f16*)(ws + alloc((size_t)NG*HH*2));
  f16* W16hh1 = (f16*)(ws + alloc((size_t)NG*HH*2));
  float* bias0 = (float*)(ws + alloc(NG*4));
  float* bias1 = (float*)(ws + alloc(NG*4));
  int* counts  = (int*)(ws + alloc(256*4));               // counts[0..7] | tailcnt[64] | ctr[64]
  int* tailcnt = counts + 64;
  int* ctr     = counts + 128;
  int* lists   = (int*)(ws + alloc(89216*4));
  int* taillist= (int*)(ws + alloc((size_t)BT*4));
  float* hf    = (float*)(ws + alloc((size_t)BB*HH*4));
  if (ws_size < off) return;  // workspace too small -> visible validation failure

  f16* AX = H0LN;  // x cast region, consumed by proj0 before H0LN written

  // persistent-grid sizing: guarantee residency via occupancy query (host-only, capture-safe)
  int nbpc = 0;
  if (hipOccupancyMaxActiveBlocksPerMultiprocessor(&nbpc, (const void*)lstm_persist, 512, 0) != hipSuccess || nbpc < 1)
    nbpc = 1;
  int pgrid = nbpc * 256;
  if (pgrid > 512) pgrid = 512;

  hipMemsetAsync(counts, 0, 256*4, stream);
  cast_f16<<<dim3(512), dim3(256), 0, stream>>>(x, AX, BT*DD/4);
  cast_f16<<<dim3(256), dim3(256), 0, stream>>>(Wih0, W16ih0, NG*DD/4);
  cast_f16<<<dim3(256), dim3(256), 0, stream>>>(Whh0, W16hh0, NG*HH/4);
  cast_f16<<<dim3(256), dim3(256), 0, stream>>>(Wih1, W16ih1, NG*HH/4);
  cast_f16<<<dim3(256), dim3(256), 0, stream>>>(Whh1, W16hh1, NG*HH/4);
  bias_add<<<dim3(8), dim3(256), 0, stream>>>(bih0, bhh0, bias0, NG);
  bias_add<<<dim3(8), dim3(256), 0, stream>>>(bih1, bhh1, bias1, NG);
  build_lists<<<dim3(BB), dim3(512), 0, stream>>>(mask, counts, lists, tailcnt, taillist);

  // ---- layer 0 ----
  proj_gemm<<<dim3((BT/128)*(NG/128)), dim3(256), 0, stream>>>(AX, W16ih0, bias0, G, DD);
  lstm_persist<<<dim3(pgrid), dim3(512), 0, stream>>>(W16hh0, G, HS, CS, mask,
      counts, lists, tailcnt, taillist, ctr, g0, be0, H0LN, 1);

  // ---- layer 1 ----
  proj_gemm<<<dim3((BT/128)*(NG/128)), dim3(256), 0, stream>>>(H0LN, W16ih1, bias1, G, HH);
  lstm_persist<<<dim3(pgrid), dim3(512), 0, stream>>>(W16hh1, G, HS, CS, mask,
      counts, lists, tailcnt, taillist, ctr + 32, g1, be1, (f16*)nullptr, 0);

  // ---- head ----
  ln_last<<<dim3(BB), dim3(512), 0, stream>>>(HS, g1, be1, hf);
  fc_kernel<<<dim3(4, BB), dim3(256), 0, stream>>>(hf, fcW, fcb, out);
}

// Round 3
// 2131.135 us; speedup vs baseline: 1.3321x; 1.3321x over previous
//
#include <hip/hip_runtime.h>
#include <stdint.h>

#define BB 64
#define TT 512
#define DD 256
#define HH 512
#define NG 2048
#define BT (BB*TT)
#define NCLS 1000
#define MAXS 12

typedef _Float16 f16;
typedef _Float16 f16x2 __attribute__((ext_vector_type(2)));
typedef _Float16 f16x4 __attribute__((ext_vector_type(4)));
typedef _Float16 f16x8 __attribute__((ext_vector_type(8)));
typedef float f32x4 __attribute__((ext_vector_type(4)));

// bucket list offsets: OFF[s] = 64 * sum_{s'<s} ceil(512/(s'+1)); capacity 101952
__device__ const int d_OFF[MAXS] = {0,32768,49152,60096,68288,74880,80384,85120,89216,92864,96192,99200};

__device__ __forceinline__ float sigf(float x) { return 1.0f / (1.0f + __expf(-x)); }
__device__ __forceinline__ float tanh_(float x) {
  float e = __expf(-2.0f * fabsf(x));
  float r = (1.0f - e) / (1.0f + e);
  return copysignf(r, x);
}
__device__ __forceinline__ f32x4 mfma16(f16x8 a, f16x8 b, f32x4 c) {
  return __builtin_amdgcn_mfma_f32_16x16x32_f16(a, b, c, 0, 0, 0);
}
__device__ __forceinline__ void gload16(const void* g, void* l) {
  __builtin_amdgcn_global_load_lds((const __attribute__((address_space(1))) void*)g,
                                   (__attribute__((address_space(3))) void*)l, 16, 0, 0);
}

// ---------------- generic f32 -> f16 cast (vectorized) ----------------
__global__ __launch_bounds__(256) void cast_f16(const float* __restrict__ s, f16* __restrict__ d, int n4) {
  int i = blockIdx.x * 256 + threadIdx.x;
  int stride = gridDim.x * 256;
  for (; i < n4; i += stride) {
    float4 v = ((const float4*)s)[i];
    f16x4 o = { (f16)v.x, (f16)v.y, (f16)v.z, (f16)v.w };
    ((f16x4*)d)[i] = o;
  }
}

__global__ __launch_bounds__(256) void bias_add(const float* __restrict__ a, const float* __restrict__ b,
                                                float* __restrict__ o, int n) {
  int i = blockIdx.x * 256 + threadIdx.x;
  if (i < n) o[i] = a[i] + b[i];
}

// ---------------- segment bucket lists (shared by both layers; same mask) ----------------
__global__ __launch_bounds__(512) void build_lists(const float* __restrict__ mask,
    int* __restrict__ counts, int* __restrict__ lists,
    int* __restrict__ tailcnt, int* __restrict__ taillist) {
  int b = blockIdx.x, t = threadIdx.x;
  __shared__ float sm[512];
  sm[t] = mask[b*TT + t];
  __syncthreads();
  int run = 0;
  for (int j = 1; j <= MAXS; ++j) {
    if (t - j < 0) break;
    if (sm[t - j] != 0.0f) run++; else break;
  }
  bool tail = (run >= MAXS);
  if (!tail) {
    int slot = atomicAdd(&counts[run], 1);
    lists[d_OFF[run] + slot] = b*TT + t;
  }
  // ordered (by t) per-batch list of tail positions via block scan
  unsigned long long bal = __ballot(tail);
  int lane = t & 63, w = t >> 6;
  int wpre = __popcll(bal & ((1ull << lane) - 1ull));
  __shared__ int wsum[8];
  if (lane == 0) wsum[w] = __popcll(bal);
  __syncthreads();
  int base = 0;
  for (int i = 0; i < w; ++i) base += wsum[i];
  if (tail) taillist[b*TT + base + wpre] = t;
  if (t == 0) {
    int tot = 0;
    for (int i = 0; i < 8; ++i) tot += wsum[i];
    tailcnt[b] = tot;
  }
}

// ---------------- projection GEMM: C[M][2048] = A[M][K] @ W[2048][K]^T + bias ----------------
__global__ __launch_bounds__(256) void proj_gemm(const f16* __restrict__ A,
    const f16* __restrict__ W, const float* __restrict__ bias,
    f16* __restrict__ C, int K) {
  __shared__ __align__(16) f16 smem[128*128];
  f16* As = smem;
  f16* Bs = smem + 128*64;
  const int nwg = gridDim.x;
  const int cpx = nwg >> 3;
  const int b0i = blockIdx.x;
  const int swz = (b0i & 7) * cpx + (b0i >> 3);
  const int m0 = (swz >> 4) * 128;
  const int n0 = (swz & 15) * 128;
  const int tid = threadIdx.x;
  const int lane = tid & 63;
  const int w = tid >> 6;
  const int srg = lane >> 3;
  const int scol = lane & 7;
  f32x4 acc[4][4] = {};
  for (int k0 = 0; k0 < K; k0 += 64) {
#pragma unroll
    for (int i = 0; i < 4; ++i) {
      int r0 = (i*4 + w) * 8;
      int row = r0 + srg;
      int cg = scol ^ (row & 7);
      gload16(A + (size_t)(m0 + row)*K + k0 + cg*8, As + r0*64);
      gload16(W + (size_t)(n0 + row)*K + k0 + cg*8, Bs + r0*64);
    }
    __syncthreads();
    {
      const int wm = (w >> 1) * 64;
      const int wn = (w & 1) * 64;
      const int cl = lane & 15;
      const int kq = lane >> 4;
#pragma unroll
      for (int ks = 0; ks < 2; ++ks) {
        int kc = ks*4 + kq;
        f16x8 af[4], bf[4];
#pragma unroll
        for (int mi = 0; mi < 4; ++mi) {
          int row = wm + mi*16 + cl;
          af[mi] = *(const f16x8*)(As + row*64 + ((kc ^ (row & 7)) * 8));
        }
#pragma unroll
        for (int ni = 0; ni < 4; ++ni) {
          int row = wn + ni*16 + cl;
          bf[ni] = *(const f16x8*)(Bs + row*64 + ((kc ^ (row & 7)) * 8));
        }
#pragma unroll
        for (int mi = 0; mi < 4; ++mi)
#pragma unroll
          for (int ni = 0; ni < 4; ++ni)
            acc[mi][ni] = mfma16(af[mi], bf[ni], acc[mi][ni]);
      }
    }
    __syncthreads();
  }
  {
    const int wm = (w >> 1) * 64;
    const int wn = (w & 1) * 64;
    const int cl = lane & 15;
    const int rq = lane >> 4;
#pragma unroll
    for (int ni = 0; ni < 4; ++ni) {
      int col = wn + ni*16 + cl;
      float bb = bias[n0 + col];
#pragma unroll
      for (int mi = 0; mi < 4; ++mi)
#pragma unroll
        for (int r = 0; r < 4; ++r)
          smem[(wm + mi*16 + rq*4 + r)*128 + col] = (f16)(acc[mi][ni][r] + bb);
    }
  }
  __syncthreads();
#pragma unroll
  for (int p = 0; p < 8; ++p) {
    int row = p*16 + (tid >> 4);
    int ch = tid & 15;
    f16x8 v = *(const f16x8*)(smem + row*128 + ch*8);
    *(f16x8*)(C + (size_t)(m0 + row)*NG + n0 + ch*8) = v;
  }
}

// ---------------- bucket 0: segment starts (h_prev = c_prev = 0), 4 rows/block ----------------
__global__ __launch_bounds__(512) void lstm_step0(const f16* __restrict__ G,
    f16* __restrict__ HS, f16* __restrict__ CS, const float* __restrict__ mask,
    const int* __restrict__ counts, const int* __restrict__ lists) {
  int cnt = counts[0];
  int i = blockIdx.x * 4 + (threadIdx.x >> 7);
  if (i >= cnt) return;
  int row = lists[i];
  int j4 = (threadIdx.x & 127) * 4;
  size_t gb = (size_t)row * NG;
  f16x4 vi = *(const f16x4*)(G + gb + j4);
  f16x4 vg = *(const f16x4*)(G + gb + 1024 + j4);
  f16x4 vo = *(const f16x4*)(G + gb + 1536 + j4);
  float m = mask[row];
  f16x4 hv, cv;
#pragma unroll
  for (int e = 0; e < 4; ++e) {
    float c = sigf((float)vi[e]) * tanh_((float)vg[e]);
    float h = sigf((float)vo[e]) * tanh_(c);
    hv[e] = (f16)(h*m); cv[e] = (f16)(c*m);
  }
  *(f16x4*)(HS + (size_t)row*HH + j4) = hv;
  *(f16x4*)(CS + (size_t)row*HH + j4) = cv;
}

// ---------------- bucket s (1..11): tiled MFMA step ----------------
// 512 thr = 8 waves (2 row-groups x 4 j-groups). Tile: 128 gathered rows x 64 j x 4 gates.
// A (gathered HS rows) and B (Whh, 4 gate sections) staged in LDS via global_load_lds w16
// with pre-swizzled global source (rule #21), XOR-swizzle on ds_read.
__global__ __launch_bounds__(512) void lstm_step(const f16* __restrict__ Wh,
    const f16* __restrict__ G, f16* __restrict__ HS, f16* __restrict__ CS,
    const float* __restrict__ mask, const int* __restrict__ counts,
    const int* __restrict__ lists, int s) {
  const int cnt = counts[s];
  const int mbase = blockIdx.x * 128;
  if (mbase >= cnt) return;
  const int j0 = blockIdx.y * 64;
  __shared__ __align__(16) f16 As[128*64];   // 16KB
  __shared__ __align__(16) f16 Bs[256*64];   // 32KB, grow = gate*64 + jj
  __shared__ int ridx[128];
  __shared__ float rmk[128];
  const int* lst = lists + d_OFF[s];
  const int tid = threadIdx.x;
  const int lane = tid & 63;
  const int w = tid >> 6;
  if (tid < 128) {
    int i = mbase + tid;
    int r = (i < cnt) ? lst[i] : -1;
    ridx[tid] = r;
    rmk[tid] = (r >= 0) ? mask[r] : 0.0f;
  }
  __syncthreads();

  // precompute staging addresses (per-thread): A 2 chunks, B 4 chunks per K-iter
  int arow[2], acs[2];
  const f16* asrc[2];
#pragma unroll
  for (int p = 0; p < 2; ++p) {
    int cid = tid + p*512;
    int r = cid >> 3, c = cid & 7;
    arow[p] = r;
    acs[p] = c ^ (r & 7);
    int rr = ridx[r];
    int sr = (rr >= 1 ? rr : 1) - 1;
    asrc[p] = HS + (size_t)sr*HH + acs[p]*8;
  }
  const f16* bsrc[4];
#pragma unroll
  for (int p = 0; p < 4; ++p) {
    int cid = tid + p*512;
    int grow = cid >> 3, c = cid & 7;
    int cs = c ^ (grow & 7);
    int wrow = (grow >> 6)*512 + j0 + (grow & 63);
    bsrc[p] = Wh + (size_t)wrow*HH + cs*8;
  }

  const int rg = w >> 2;          // 0..1 : rows [rg*64, rg*64+64)
  const int jg = w & 3;           // 0..3 : j-cols [jg*16, +16)
  const int cl = lane & 15;
  const int kq = lane >> 4;
  f32x4 acc[4][4] = {};           // [row-frag][gate]

  for (int k0 = 0; k0 < HH; k0 += 64) {
#pragma unroll
    for (int p = 0; p < 2; ++p)
      gload16(asrc[p] + k0, As + (tid + p*512)*8);
#pragma unroll
    for (int p = 0; p < 4; ++p)
      gload16(bsrc[p] + k0, Bs + (tid + p*512)*8);
    __syncthreads();
#pragma unroll
    for (int ks = 0; ks < 2; ++ks) {
      int kc = ks*4 + kq;
      f16x8 af[4], bf[4];
#pragma unroll
      for (int mi = 0; mi < 4; ++mi) {
        int row = rg*64 + mi*16 + cl;
        af[mi] = *(const f16x8*)(As + row*64 + ((kc ^ (row & 7))*8));
      }
#pragma unroll
      for (int g = 0; g < 4; ++g) {
        int brow = g*64 + jg*16 + cl;
        bf[g] = *(const f16x8*)(Bs + brow*64 + ((kc ^ (brow & 7))*8));
      }
#pragma unroll
      for (int mi = 0; mi < 4; ++mi)
#pragma unroll
        for (int g = 0; g < 4; ++g)
          acc[mi][g] = mfma16(af[mi], bf[g], acc[mi][g]);
    }
    __syncthreads();
  }

  const int j = j0 + jg*16 + cl;
#pragma unroll
  for (int mi = 0; mi < 4; ++mi)
#pragma unroll
    for (int r = 0; r < 4; ++r) {
      int slot = rg*64 + mi*16 + kq*4 + r;
      int row = ridx[slot];
      if (row >= 0) {
        size_t gb = (size_t)row * NG;
        float gi = acc[mi][0][r] + (float)G[gb + j];
        float gf = acc[mi][1][r] + (float)G[gb + 512 + j];
        float gg = acc[mi][2][r] + (float)G[gb + 1024 + j];
        float go = acc[mi][3][r] + (float)G[gb + 1536 + j];
        float cp = (float)CS[(size_t)(row - 1)*HH + j];
        float c = sigf(gf)*cp + sigf(gi)*tanh_(gg);
        float h = sigf(go)*tanh_(c);
        float m = rmk[slot];
        HS[(size_t)row*HH + j] = (f16)(h*m);
        CS[(size_t)row*HH + j] = (f16)(c*m);
      }
    }
}

// ---------------- tail: run >= 12, sequential per batch (rare) ----------------
// wave-coalesced matvec: wave w computes outputs o = w*256..w*256+255, full-row dot + shfl reduce
__global__ __launch_bounds__(512) void lstm_tail(const f16* __restrict__ Wh,
    const f16* __restrict__ G, f16* __restrict__ HS, f16* __restrict__ CS,
    const float* __restrict__ mask, const int* __restrict__ tailcnt,
    const int* __restrict__ taillist) {
  int b = blockIdx.x;
  int n = tailcnt[b];
  if (n == 0) return;
  int tid = threadIdx.x, lane = tid & 63, w = tid >> 6;
  __shared__ __align__(16) f16 hsh[HH];
  __shared__ float gsh[NG];
  for (int i = 0; i < n; ++i) {
    int t = taillist[b*TT + i];
    size_t row = (size_t)b*TT + t;
    if (tid < 256)
      ((uint32_t*)hsh)[tid] = ((const uint32_t*)(HS + (row - 1)*HH))[tid];
    __syncthreads();
    f16x8 hv = *(const f16x8*)(hsh + lane*8);
    for (int q = 0; q < 256; ++q) {
      int o = w*256 + q;
      f16x8 wv = *(const f16x8*)(Wh + (size_t)o*HH + lane*8);
      f16x2 h0 = {hv[0], hv[1]}, h1 = {hv[2], hv[3]}, h2 = {hv[4], hv[5]}, h3 = {hv[6], hv[7]};
      f16x2 w0 = {wv[0], wv[1]}, w1 = {wv[2], wv[3]}, w2 = {wv[4], wv[5]}, w3 = {wv[6], wv[7]};
      float p = __builtin_amdgcn_fdot2(w0, h0, 0.0f, false);
      p = __builtin_amdgcn_fdot2(w1, h1, p, false);
      p = __builtin_amdgcn_fdot2(w2, h2, p, false);
      p = __builtin_amdgcn_fdot2(w3, h3, p, false);
#pragma unroll
      for (int o2 = 1; o2 < 64; o2 <<= 1) p += __shfl_xor(p, o2);
      if (lane == 0) gsh[o] = p + (float)G[row*NG + o];
    }
    __syncthreads();
    {
      float cp = (float)CS[(row - 1)*HH + tid];
      float c = sigf(gsh[512 + tid])*cp + sigf(gsh[tid])*tanh_(gsh[1024 + tid]);
      float h = sigf(gsh[1536 + tid])*tanh_(c);
      float m = mask[row];
      HS[row*HH + tid] = (f16)(h*m);
      CS[row*HH + tid] = (f16)(c*m);
    }
    __syncthreads();
  }
}

// ---------------- relu + layernorm, wave-per-row ----------------
__global__ __launch_bounds__(512) void ln_relu(const f16* __restrict__ in,
    const float* __restrict__ g, const float* __restrict__ be,
    f16* __restrict__ out) {
  int lane = threadIdx.x & 63, w = threadIdx.x >> 6;
  int row = blockIdx.x * 8 + w;
  f16x8 hv = *(const f16x8*)(in + (size_t)row*HH + lane*8);
  float xv[8]; float s1 = 0.f, s2 = 0.f;
#pragma unroll
  for (int e = 0; e < 8; ++e) { float x = fmaxf((float)hv[e], 0.f); xv[e] = x; s1 += x; s2 += x*x; }
#pragma unroll
  for (int o = 1; o < 64; o <<= 1) { s1 += __shfl_xor(s1, o); s2 += __shfl_xor(s2, o); }
  float mu = s1 * (1.0f/512.0f);
  float var = s2 * (1.0f/512.0f) - mu*mu;
  float rs = rsqrtf(var + 1e-5f);
  f16x8 ov;
#pragma unroll
  for (int e = 0; e < 8; ++e) ov[e] = (f16)((xv[e] - mu)*rs*g[lane*8+e] + be[lane*8+e]);
  *(f16x8*)(out + (size_t)row*HH + lane*8) = ov;
}

// layernorm of the final (t=T-1) hidden state, f32 output
__global__ __launch_bounds__(512) void ln_last(const f16* __restrict__ HS,
    const float* __restrict__ g, const float* __restrict__ be, float* __restrict__ out) {
  int b = blockIdx.x;
  int j = threadIdx.x;
  float x = fmaxf((float)HS[((size_t)b*TT + (TT-1))*HH + j], 0.0f);
  float s1 = x, s2 = x*x;
  for (int o = 32; o > 0; o >>= 1) { s1 += __shfl_down(s1, o); s2 += __shfl_down(s2, o); }
  __shared__ float a1[8], a2[8];
  int w = j >> 6;
  if ((j & 63) == 0) { a1[w] = s1; a2[w] = s2; }
  __syncthreads();
  if (j == 0) {
    float t1 = 0.f, t2 = 0.f;
    for (int i = 0; i < 8; ++i) { t1 += a1[i]; t2 += a2[i]; }
    a1[0] = t1; a2[0] = t2;
  }
  __syncthreads();
  float mu = a1[0] * (1.0f/512.0f);
  float var = a2[0] * (1.0f/512.0f) - mu*mu;
  float y = (x - mu) * rsqrtf(var + 1e-5f) * g[j] + be[j];
  out[b*HH + j] = y;
}

// ---------------- final classifier: out[64][1000] = hf @ fcW^T + fcb ----------------
__global__ __launch_bounds__(256) void fc_kernel(const float* __restrict__ hf,
    const float* __restrict__ W, const float* __restrict__ bias, float* __restrict__ out) {
  int b = blockIdx.y;
  int c = blockIdx.x * 256 + threadIdx.x;
  __shared__ float hsh[512];
  hsh[threadIdx.x] = hf[b*HH + threadIdx.x];
  hsh[threadIdx.x + 256] = hf[b*HH + 256 + threadIdx.x];
  __syncthreads();
  if (c < NCLS) {
    const float4* wr = (const float4*)(W + (size_t)c*HH);
    float acc = bias[c];
#pragma unroll 4
    for (int k4 = 0; k4 < 128; ++k4) {
      float4 wv = wr[k4];
      acc += wv.x*hsh[k4*4] + wv.y*hsh[k4*4+1] + wv.z*hsh[k4*4+2] + wv.w*hsh[k4*4+3];
    }
    out[b*NCLS + c] = acc;
  }
}

extern "C" void kernel_launch(void* const* d_in, const int* in_sizes, int n_in,
                              void* d_out, int out_size, void* d_ws, size_t ws_size,
                              hipStream_t stream) {
  (void)in_sizes; (void)n_in; (void)out_size;
  const float* x    = (const float*)d_in[0];
  const float* mask = (const float*)d_in[1];
  const float* Wih0 = (const float*)d_in[2];
  const float* Whh0 = (const float*)d_in[3];
  const float* bih0 = (const float*)d_in[4];
  const float* bhh0 = (const float*)d_in[5];
  const float* g0   = (const float*)d_in[6];
  const float* be0  = (const float*)d_in[7];
  const float* Wih1 = (const float*)d_in[8];
  const float* Whh1 = (const float*)d_in[9];
  const float* bih1 = (const float*)d_in[10];
  const float* bhh1 = (const float*)d_in[11];
  const float* g1   = (const float*)d_in[12];
  const float* be1  = (const float*)d_in[13];
  const float* fcW  = (const float*)d_in[14];
  const float* fcb  = (const float*)d_in[15];
  float* out = (float*)d_out;

  char* ws = (char*)d_ws;
  size_t off = 0;
  auto alloc = [&](size_t bytes) { size_t o = off; off += (bytes + 255) & ~(size_t)255; return o; };
  f16* G      = (f16*)(ws + alloc((size_t)BT*NG*2));
  f16* HS     = (f16*)(ws + alloc((size_t)BT*HH*2));
  f16* CS     = (f16*)(ws + alloc((size_t)BT*HH*2));
  f16* H0LN   = (f16*)(ws + alloc((size_t)BT*HH*2));
  f16* W16ih0 = (f16*)(ws + alloc((size_t)NG*DD*2));
  f16* W16hh0 = (f16*)(ws + alloc((size_t)NG*HH*2));
  f16* W16ih1 = (f16*)(ws + alloc((size_t)NG*HH*2));
  f16* W16hh1 = (f16*)(ws + alloc((size_t)NG*HH*2));
  float* bias0 = (float*)(ws + alloc(NG*4));
  float* bias1 = (float*)(ws + alloc(NG*4));
  int* counts  = (int*)(ws + alloc(128*4));     // counts[0..11] | tailcnt @ 64
  int* tailcnt = counts + 64;
  int* lists   = (int*)(ws + alloc(101952*4));
  int* taillist= (int*)(ws + alloc((size_t)BT*4));
  float* hf    = (float*)(ws + alloc((size_t)BB*HH*4));
  if (ws_size < off) return;

  f16* AX = H0LN;  // x-f16 region, consumed by proj0 before H0LN written

  hipMemsetAsync(counts, 0, 128*4, stream);
  cast_f16<<<dim3(512), dim3(256), 0, stream>>>(x, AX, BT*DD/4);
  cast_f16<<<dim3(256), dim3(256), 0, stream>>>(Wih0, W16ih0, NG*DD/4);
  cast_f16<<<dim3(256), dim3(256), 0, stream>>>(Whh0, W16hh0, NG*HH/4);
  cast_f16<<<dim3(256), dim3(256), 0, stream>>>(Wih1, W16ih1, NG*HH/4);
  cast_f16<<<dim3(256), dim3(256), 0, stream>>>(Whh1, W16hh1, NG*HH/4);
  bias_add<<<dim3(8), dim3(256), 0, stream>>>(bih0, bhh0, bias0, NG);
  bias_add<<<dim3(8), dim3(256), 0, stream>>>(bih1, bhh1, bias1, NG);
  build_lists<<<dim3(BB), dim3(512), 0, stream>>>(mask, counts, lists, tailcnt, taillist);

  for (int layer = 0; layer < 2; ++layer) {
    const f16* Wih16 = layer ? W16ih1 : W16ih0;
    const f16* Whh16 = layer ? W16hh1 : W16hh0;
    const float* bias = layer ? bias1 : bias0;
    const f16* Ain = layer ? H0LN : AX;
    int K = layer ? HH : DD;
    proj_gemm<<<dim3((BT/128)*(NG/128)), dim3(256), 0, stream>>>(Ain, Wih16, bias, G, K);
    lstm_step0<<<dim3(BT/4), dim3(512), 0, stream>>>(G, HS, CS, mask, counts, lists);
    for (int s = 1; s < MAXS; ++s) {
      int cap = 64 * ((TT + s) / (s + 1));
      int gx = (cap + 127) / 128;
      lstm_step<<<dim3(gx, 8), dim3(512), 0, stream>>>(Whh16, G, HS, CS, mask, counts, lists, s);
    }
    lstm_tail<<<dim3(BB), dim3(512), 0, stream>>>(Whh16, G, HS, CS, mask, tailcnt, taillist);
    if (layer == 0)
      ln_relu<<<dim3(BT/8), dim3(512), 0, stream>>>(HS, g0, be0, H0LN);
  }

  ln_last<<<dim3(BB), dim3(512), 0, stream>>>(HS, g1, be1, hf);
  fc_kernel<<<dim3(4, BB), dim3(256), 0, stream>>>(hf, fcW, fcb, out);
}

// Round 4
// 1319.949 us; speedup vs baseline: 2.1507x; 1.6146x over previous
//
#include <hip/hip_runtime.h>
#include <stdint.h>

#define BB 64
#define TT 512
#define DD 256
#define HH 512
#define NG 2048
#define BT (BB*TT)
#define NCLS 1000
#define MAXS 16

typedef _Float16 f16;
typedef _Float16 f16x2 __attribute__((ext_vector_type(2)));
typedef _Float16 f16x4 __attribute__((ext_vector_type(4)));
typedef _Float16 f16x8 __attribute__((ext_vector_type(8)));
typedef float f32x4 __attribute__((ext_vector_type(4)));

// bucket list offsets: OFF[s] = 64 * sum_{s'<s} ceil(512/(s'+1)); capacity 111168
__device__ const int d_OFF[MAXS] = {0,32768,49152,60096,68288,74880,80384,85120,
                                    89216,92864,96192,99200,101952,104512,106880,109120};

__device__ __forceinline__ float sigf(float x) { return 1.0f / (1.0f + __expf(-x)); }
__device__ __forceinline__ float tanh_(float x) {
  float e = __expf(-2.0f * fabsf(x));
  float r = (1.0f - e) / (1.0f + e);
  return copysignf(r, x);
}
__device__ __forceinline__ f32x4 mfma16(f16x8 a, f16x8 b, f32x4 c) {
  return __builtin_amdgcn_mfma_f32_16x16x32_f16(a, b, c, 0, 0, 0);
}
__device__ __forceinline__ void gload16(const void* g, void* l) {
  __builtin_amdgcn_global_load_lds((const __attribute__((address_space(1))) void*)g,
                                   (__attribute__((address_space(3))) void*)l, 16, 0, 0);
}

// ---------------- generic f32 -> f16 cast (vectorized) ----------------
__global__ __launch_bounds__(256) void cast_f16(const float* __restrict__ s, f16* __restrict__ d, int n4) {
  int i = blockIdx.x * 256 + threadIdx.x;
  int stride = gridDim.x * 256;
  for (; i < n4; i += stride) {
    float4 v = ((const float4*)s)[i];
    f16x4 o = { (f16)v.x, (f16)v.y, (f16)v.z, (f16)v.w };
    ((f16x4*)d)[i] = o;
  }
}

__global__ __launch_bounds__(256) void bias_add(const float* __restrict__ a, const float* __restrict__ b,
                                                float* __restrict__ o, int n) {
  int i = blockIdx.x * 256 + threadIdx.x;
  if (i < n) o[i] = a[i] + b[i];
}

// ---------------- segment bucket lists (shared by both layers; same mask) ----------------
__global__ __launch_bounds__(512) void build_lists(const float* __restrict__ mask,
    int* __restrict__ counts, int* __restrict__ lists,
    int* __restrict__ tailcnt, int* __restrict__ taillist) {
  int b = blockIdx.x, t = threadIdx.x;
  __shared__ float sm[512];
  sm[t] = mask[b*TT + t];
  __syncthreads();
  int run = 0;
  for (int j = 1; j <= MAXS; ++j) {
    if (t - j < 0) break;
    if (sm[t - j] != 0.0f) run++; else break;
  }
  bool tail = (run >= MAXS);
  if (!tail) {
    int slot = atomicAdd(&counts[run], 1);
    lists[d_OFF[run] + slot] = b*TT + t;
  }
  // ordered (by t) per-batch list of tail positions via block scan
  unsigned long long bal = __ballot(tail);
  int lane = t & 63, w = t >> 6;
  int wpre = __popcll(bal & ((1ull << lane) - 1ull));
  __shared__ int wsum[8];
  if (lane == 0) wsum[w] = __popcll(bal);
  __syncthreads();
  int base = 0;
  for (int i = 0; i < w; ++i) base += wsum[i];
  if (tail) taillist[b*TT + base + wpre] = t;
  if (t == 0) {
    int tot = 0;
    for (int i = 0; i < 8; ++i) tot += wsum[i];
    tailcnt[b] = tot;
  }
}

// ---------------- projection GEMM: C[M][2048] = A[M][K] @ W[2048][K]^T + bias ----------------
__global__ __launch_bounds__(256) void proj_gemm(const f16* __restrict__ A,
    const f16* __restrict__ W, const float* __restrict__ bias,
    f16* __restrict__ C, int K) {
  __shared__ __align__(16) f16 smem[128*128];
  f16* As = smem;
  f16* Bs = smem + 128*64;
  const int nwg = gridDim.x;
  const int cpx = nwg >> 3;
  const int b0i = blockIdx.x;
  const int swz = (b0i & 7) * cpx + (b0i >> 3);
  const int m0 = (swz >> 4) * 128;
  const int n0 = (swz & 15) * 128;
  const int tid = threadIdx.x;
  const int lane = tid & 63;
  const int w = tid >> 6;
  const int srg = lane >> 3;
  const int scol = lane & 7;
  f32x4 acc[4][4] = {};
  for (int k0 = 0; k0 < K; k0 += 64) {
#pragma unroll
    for (int i = 0; i < 4; ++i) {
      int r0 = (i*4 + w) * 8;
      int row = r0 + srg;
      int cg = scol ^ (row & 7);
      gload16(A + (size_t)(m0 + row)*K + k0 + cg*8, As + r0*64);
      gload16(W + (size_t)(n0 + row)*K + k0 + cg*8, Bs + r0*64);
    }
    __syncthreads();
    {
      const int wm = (w >> 1) * 64;
      const int wn = (w & 1) * 64;
      const int cl = lane & 15;
      const int kq = lane >> 4;
#pragma unroll
      for (int ks = 0; ks < 2; ++ks) {
        int kc = ks*4 + kq;
        f16x8 af[4], bf[4];
#pragma unroll
        for (int mi = 0; mi < 4; ++mi) {
          int row = wm + mi*16 + cl;
          af[mi] = *(const f16x8*)(As + row*64 + ((kc ^ (row & 7)) * 8));
        }
#pragma unroll
        for (int ni = 0; ni < 4; ++ni) {
          int row = wn + ni*16 + cl;
          bf[ni] = *(const f16x8*)(Bs + row*64 + ((kc ^ (row & 7)) * 8));
        }
#pragma unroll
        for (int mi = 0; mi < 4; ++mi)
#pragma unroll
          for (int ni = 0; ni < 4; ++ni)
            acc[mi][ni] = mfma16(af[mi], bf[ni], acc[mi][ni]);
      }
    }
    __syncthreads();
  }
  {
    const int wm = (w >> 1) * 64;
    const int wn = (w & 1) * 64;
    const int cl = lane & 15;
    const int rq = lane >> 4;
#pragma unroll
    for (int ni = 0; ni < 4; ++ni) {
      int col = wn + ni*16 + cl;
      float bb = bias[n0 + col];
#pragma unroll
      for (int mi = 0; mi < 4; ++mi)
#pragma unroll
        for (int r = 0; r < 4; ++r)
          smem[(wm + mi*16 + rq*4 + r)*128 + col] = (f16)(acc[mi][ni][r] + bb);
    }
  }
  __syncthreads();
#pragma unroll
  for (int p = 0; p < 8; ++p) {
    int row = p*16 + (tid >> 4);
    int ch = tid & 15;
    f16x8 v = *(const f16x8*)(smem + row*128 + ch*8);
    *(f16x8*)(C + (size_t)(m0 + row)*NG + n0 + ch*8) = v;
  }
}

// ---------------- bucket 0: segment starts (h_prev = c_prev = 0), 4 rows/block ----------------
__global__ __launch_bounds__(512) void lstm_step0(const f16* __restrict__ G,
    f16* __restrict__ HS, f16* __restrict__ CS, const float* __restrict__ mask,
    const int* __restrict__ counts, const int* __restrict__ lists) {
  int cnt = counts[0];
  int i = blockIdx.x * 4 + (threadIdx.x >> 7);
  if (i >= cnt) return;
  int row = lists[i];
  int j4 = (threadIdx.x & 127) * 4;
  size_t gb = (size_t)row * NG;
  f16x4 vi = *(const f16x4*)(G + gb + j4);
  f16x4 vg = *(const f16x4*)(G + gb + 1024 + j4);
  f16x4 vo = *(const f16x4*)(G + gb + 1536 + j4);
  float m = mask[row];
  f16x4 hv, cv;
#pragma unroll
  for (int e = 0; e < 4; ++e) {
    float c = sigf((float)vi[e]) * tanh_((float)vg[e]);
    float h = sigf((float)vo[e]) * tanh_(c);
    hv[e] = (f16)(h*m); cv[e] = (f16)(c*m);
  }
  *(f16x4*)(HS + (size_t)row*HH + j4) = hv;
  *(f16x4*)(CS + (size_t)row*HH + j4) = cv;
}

// ---------------- bucket s (1..15): tiled MFMA step ----------------
// 512 thr = 8 waves (2 row-groups x 4 j-groups). Tile: 128 gathered rows x 64 j x 4 gates.
__global__ __launch_bounds__(512) void lstm_step(const f16* __restrict__ Wh,
    const f16* __restrict__ G, f16* __restrict__ HS, f16* __restrict__ CS,
    const float* __restrict__ mask, const int* __restrict__ counts,
    const int* __restrict__ lists, int s) {
  const int cnt = counts[s];
  const int mbase = blockIdx.x * 128;
  if (mbase >= cnt) return;
  const int j0 = blockIdx.y * 64;
  __shared__ __align__(16) f16 As[128*64];   // 16KB
  __shared__ __align__(16) f16 Bs[256*64];   // 32KB, grow = gate*64 + jj
  __shared__ int ridx[128];
  __shared__ float rmk[128];
  const int* lst = lists + d_OFF[s];
  const int tid = threadIdx.x;
  const int lane = tid & 63;
  const int w = tid >> 6;
  if (tid < 128) {
    int i = mbase + tid;
    int r = (i < cnt) ? lst[i] : -1;
    ridx[tid] = r;
    rmk[tid] = (r >= 0) ? mask[r] : 0.0f;
  }
  __syncthreads();

  // precompute staging addresses (per-thread): A 2 chunks, B 4 chunks per K-iter
  const f16* asrc[2];
#pragma unroll
  for (int p = 0; p < 2; ++p) {
    int cid = tid + p*512;
    int r = cid >> 3, c = cid & 7;
    int cs = c ^ (r & 7);
    int rr = ridx[r];
    int sr = (rr >= 1 ? rr : 1) - 1;
    asrc[p] = HS + (size_t)sr*HH + cs*8;
  }
  const f16* bsrc[4];
#pragma unroll
  for (int p = 0; p < 4; ++p) {
    int cid = tid + p*512;
    int grow = cid >> 3, c = cid & 7;
    int cs = c ^ (grow & 7);
    int wrow = (grow >> 6)*512 + j0 + (grow & 63);
    bsrc[p] = Wh + (size_t)wrow*HH + cs*8;
  }

  const int rg = w >> 2;          // 0..1 : rows [rg*64, rg*64+64)
  const int jg = w & 3;           // 0..3 : j-cols [jg*16, +16)
  const int cl = lane & 15;
  const int kq = lane >> 4;
  f32x4 acc[4][4] = {};           // [row-frag][gate]

  for (int k0 = 0; k0 < HH; k0 += 64) {
#pragma unroll
    for (int p = 0; p < 2; ++p)
      gload16(asrc[p] + k0, As + (tid + p*512)*8);
#pragma unroll
    for (int p = 0; p < 4; ++p)
      gload16(bsrc[p] + k0, Bs + (tid + p*512)*8);
    __syncthreads();
#pragma unroll
    for (int ks = 0; ks < 2; ++ks) {
      int kc = ks*4 + kq;
      f16x8 af[4], bf[4];
#pragma unroll
      for (int mi = 0; mi < 4; ++mi) {
        int row = rg*64 + mi*16 + cl;
        af[mi] = *(const f16x8*)(As + row*64 + ((kc ^ (row & 7))*8));
      }
#pragma unroll
      for (int g = 0; g < 4; ++g) {
        int brow = g*64 + jg*16 + cl;
        bf[g] = *(const f16x8*)(Bs + brow*64 + ((kc ^ (brow & 7))*8));
      }
#pragma unroll
      for (int mi = 0; mi < 4; ++mi)
#pragma unroll
        for (int g = 0; g < 4; ++g)
          acc[mi][g] = mfma16(af[mi], bf[g], acc[mi][g]);
    }
    __syncthreads();
  }

  const int j = j0 + jg*16 + cl;
#pragma unroll
  for (int mi = 0; mi < 4; ++mi)
#pragma unroll
    for (int r = 0; r < 4; ++r) {
      int slot = rg*64 + mi*16 + kq*4 + r;
      int row = ridx[slot];
      if (row >= 0) {
        size_t gb = (size_t)row * NG;
        float gi = acc[mi][0][r] + (float)G[gb + j];
        float gf = acc[mi][1][r] + (float)G[gb + 512 + j];
        float gg = acc[mi][2][r] + (float)G[gb + 1024 + j];
        float go = acc[mi][3][r] + (float)G[gb + 1536 + j];
        float cp = (float)CS[(size_t)(row - 1)*HH + j];
        float c = sigf(gf)*cp + sigf(gi)*tanh_(gg);
        float h = sigf(go)*tanh_(c);
        float m = rmk[slot];
        HS[(size_t)row*HH + j] = (f16)(h*m);
        CS[(size_t)row*HH + j] = (f16)(c*m);
      }
    }
}

// ---------------- tail: run >= 16, sequential per batch (expected empty) ----------------
// per-thread-output dot (512 thr x 4 outputs), no per-output cross-lane reduce
__global__ __launch_bounds__(512) void lstm_tail(const f16* __restrict__ Wh,
    const f16* __restrict__ G, f16* __restrict__ HS, f16* __restrict__ CS,
    const float* __restrict__ mask, const int* __restrict__ tailcnt,
    const int* __restrict__ taillist) {
  int b = blockIdx.x;
  int n = tailcnt[b];
  if (n == 0) return;
  int tid = threadIdx.x;
  __shared__ __align__(4) f16 hsh[HH];
  __shared__ float gsh[NG];
  for (int i = 0; i < n; ++i) {
    int t = taillist[b*TT + i];
    size_t row = (size_t)b*TT + t;
    if (tid < 256)
      ((uint32_t*)hsh)[tid] = ((const uint32_t*)(HS + (row - 1)*HH))[tid];
    __syncthreads();
#pragma unroll
    for (int rep = 0; rep < 4; ++rep) {
      int o = tid + rep*512;
      float a = (float)G[row*NG + o];
      const f16x8* wr = (const f16x8*)(Wh + (size_t)o*HH);
      const f16x2* hp = (const f16x2*)hsh;
#pragma unroll 4
      for (int k8 = 0; k8 < 64; ++k8) {
        f16x8 wv = wr[k8];
        f16x2 p0 = {wv[0], wv[1]}, p1 = {wv[2], wv[3]}, p2 = {wv[4], wv[5]}, p3 = {wv[6], wv[7]};
        a = __builtin_amdgcn_fdot2(p0, hp[k8*4+0], a, false);
        a = __builtin_amdgcn_fdot2(p1, hp[k8*4+1], a, false);
        a = __builtin_amdgcn_fdot2(p2, hp[k8*4+2], a, false);
        a = __builtin_amdgcn_fdot2(p3, hp[k8*4+3], a, false);
      }
      gsh[o] = a;
    }
    __syncthreads();
    {
      float cp = (float)CS[(row - 1)*HH + tid];
      float c = sigf(gsh[512 + tid])*cp + sigf(gsh[tid])*tanh_(gsh[1024 + tid]);
      float h = sigf(gsh[1536 + tid])*tanh_(c);
      float m = mask[row];
      HS[row*HH + tid] = (f16)(h*m);
      CS[row*HH + tid] = (f16)(c*m);
    }
    __syncthreads();
  }
}

// ---------------- relu + layernorm, wave-per-row ----------------
__global__ __launch_bounds__(512) void ln_relu(const f16* __restrict__ in,
    const float* __restrict__ g, const float* __restrict__ be,
    f16* __restrict__ out) {
  int lane = threadIdx.x & 63, w = threadIdx.x >> 6;
  int row = blockIdx.x * 8 + w;
  f16x8 hv = *(const f16x8*)(in + (size_t)row*HH + lane*8);
  float xv[8]; float s1 = 0.f, s2 = 0.f;
#pragma unroll
  for (int e = 0; e < 8; ++e) { float x = fmaxf((float)hv[e], 0.f); xv[e] = x; s1 += x; s2 += x*x; }
#pragma unroll
  for (int o = 1; o < 64; o <<= 1) { s1 += __shfl_xor(s1, o); s2 += __shfl_xor(s2, o); }
  float mu = s1 * (1.0f/512.0f);
  float var = s2 * (1.0f/512.0f) - mu*mu;
  float rs = rsqrtf(var + 1e-5f);
  f16x8 ov;
#pragma unroll
  for (int e = 0; e < 8; ++e) ov[e] = (f16)((xv[e] - mu)*rs*g[lane*8+e] + be[lane*8+e]);
  *(f16x8*)(out + (size_t)row*HH + lane*8) = ov;
}

// layernorm of the final (t=T-1) hidden state, f32 output
__global__ __launch_bounds__(512) void ln_last(const f16* __restrict__ HS,
    const float* __restrict__ g, const float* __restrict__ be, float* __restrict__ out) {
  int b = blockIdx.x;
  int j = threadIdx.x;
  float x = fmaxf((float)HS[((size_t)b*TT + (TT-1))*HH + j], 0.0f);
  float s1 = x, s2 = x*x;
  for (int o = 32; o > 0; o >>= 1) { s1 += __shfl_down(s1, o); s2 += __shfl_down(s2, o); }
  __shared__ float a1[8], a2[8];
  int w = j >> 6;
  if ((j & 63) == 0) { a1[w] = s1; a2[w] = s2; }
  __syncthreads();
  if (j == 0) {
    float t1 = 0.f, t2 = 0.f;
    for (int i = 0; i < 8; ++i) { t1 += a1[i]; t2 += a2[i]; }
    a1[0] = t1; a2[0] = t2;
  }
  __syncthreads();
  float mu = a1[0] * (1.0f/512.0f);
  float var = a2[0] * (1.0f/512.0f) - mu*mu;
  float y = (x - mu) * rsqrtf(var + 1e-5f) * g[j] + be[j];
  out[b*HH + j] = y;
}

// ---------------- final classifier: out[64][1000] = hf @ fcW^T + fcb ----------------
__global__ __launch_bounds__(256) void fc_kernel(const float* __restrict__ hf,
    const float* __restrict__ W, const float* __restrict__ bias, float* __restrict__ out) {
  int b = blockIdx.y;
  int c = blockIdx.x * 256 + threadIdx.x;
  __shared__ float hsh[512];
  hsh[threadIdx.x] = hf[b*HH + threadIdx.x];
  hsh[threadIdx.x + 256] = hf[b*HH + 256 + threadIdx.x];
  __syncthreads();
  if (c < NCLS) {
    const float4* wr = (const float4*)(W + (size_t)c*HH);
    float acc = bias[c];
#pragma unroll 4
    for (int k4 = 0; k4 < 128; ++k4) {
      float4 wv = wr[k4];
      acc += wv.x*hsh[k4*4] + wv.y*hsh[k4*4+1] + wv.z*hsh[k4*4+2] + wv.w*hsh[k4*4+3];
    }
    out[b*NCLS + c] = acc;
  }
}

extern "C" void kernel_launch(void* const* d_in, const int* in_sizes, int n_in,
                              void* d_out, int out_size, void* d_ws, size_t ws_size,
                              hipStream_t stream) {
  (void)in_sizes; (void)n_in; (void)out_size;
  const float* x    = (const float*)d_in[0];
  const float* mask = (const float*)d_in[1];
  const float* Wih0 = (const float*)d_in[2];
  const float* Whh0 = (const float*)d_in[3];
  const float* bih0 = (const float*)d_in[4];
  const float* bhh0 = (const float*)d_in[5];
  const float* g0   = (const float*)d_in[6];
  const float* be0  = (const float*)d_in[7];
  const float* Wih1 = (const float*)d_in[8];
  const float* Whh1 = (const float*)d_in[9];
  const float* bih1 = (const float*)d_in[10];
  const float* bhh1 = (const float*)d_in[11];
  const float* g1   = (const float*)d_in[12];
  const float* be1  = (const float*)d_in[13];
  const float* fcW  = (const float*)d_in[14];
  const float* fcb  = (const float*)d_in[15];
  float* out = (float*)d_out;

  char* ws = (char*)d_ws;
  size_t off = 0;
  auto alloc = [&](size_t bytes) { size_t o = off; off += (bytes + 255) & ~(size_t)255; return o; };
  f16* G      = (f16*)(ws + alloc((size_t)BT*NG*2));
  f16* HS     = (f16*)(ws + alloc((size_t)BT*HH*2));
  f16* CS     = (f16*)(ws + alloc((size_t)BT*HH*2));
  f16* H0LN   = (f16*)(ws + alloc((size_t)BT*HH*2));
  f16* W16ih0 = (f16*)(ws + alloc((size_t)NG*DD*2));
  f16* W16hh0 = (f16*)(ws + alloc((size_t)NG*HH*2));
  f16* W16ih1 = (f16*)(ws + alloc((size_t)NG*HH*2));
  f16* W16hh1 = (f16*)(ws + alloc((size_t)NG*HH*2));
  float* bias0 = (float*)(ws + alloc(NG*4));
  float* bias1 = (float*)(ws + alloc(NG*4));
  int* counts  = (int*)(ws + alloc(128*4));     // counts[0..15] | tailcnt @ 64
  int* tailcnt = counts + 64;
  int* lists   = (int*)(ws + alloc(111168*4));
  int* taillist= (int*)(ws + alloc((size_t)BT*4));
  float* hf    = (float*)(ws + alloc((size_t)BB*HH*4));
  if (ws_size < off) return;

  f16* AX = H0LN;  // x-f16 region, consumed by proj0 before H0LN written

  hipMemsetAsync(counts, 0, 128*4, stream);
  cast_f16<<<dim3(512), dim3(256), 0, stream>>>(x, AX, BT*DD/4);
  cast_f16<<<dim3(256), dim3(256), 0, stream>>>(Wih0, W16ih0, NG*DD/4);
  cast_f16<<<dim3(256), dim3(256), 0, stream>>>(Whh0, W16hh0, NG*HH/4);
  cast_f16<<<dim3(256), dim3(256), 0, stream>>>(Wih1, W16ih1, NG*HH/4);
  cast_f16<<<dim3(256), dim3(256), 0, stream>>>(Whh1, W16hh1, NG*HH/4);
  bias_add<<<dim3(8), dim3(256), 0, stream>>>(bih0, bhh0, bias0, NG);
  bias_add<<<dim3(8), dim3(256), 0, stream>>>(bih1, bhh1, bias1, NG);
  build_lists<<<dim3(BB), dim3(512), 0, stream>>>(mask, counts, lists, tailcnt, taillist);

  for (int layer = 0; layer < 2; ++layer) {
    const f16* Wih16 = layer ? W16ih1 : W16ih0;
    const f16* Whh16 = layer ? W16hh1 : W16hh0;
    const float* bias = layer ? bias1 : bias0;
    const f16* Ain = layer ? H0LN : AX;
    int K = layer ? HH : DD;
    proj_gemm<<<dim3((BT/128)*(NG/128)), dim3(256), 0, stream>>>(Ain, Wih16, bias, G, K);
    lstm_step0<<<dim3(BT/4), dim3(512), 0, stream>>>(G, HS, CS, mask, counts, lists);
    for (int s = 1; s < MAXS; ++s) {
      int cap = 64 * ((TT + s) / (s + 1));
      int gx = (cap + 127) / 128;
      lstm_step<<<dim3(gx, 8), dim3(512), 0, stream>>>(Whh16, G, HS, CS, mask, counts, lists, s);
    }
    lstm_tail<<<dim3(BB), dim3(512), 0, stream>>>(Whh16, G, HS, CS, mask, tailcnt, taillist);
    if (layer == 0)
      ln_relu<<<dim3(BT/8), dim3(512), 0, stream>>>(HS, g0, be0, H0LN);
  }

  ln_last<<<dim3(BB), dim3(512), 0, stream>>>(HS, g1, be1, hf);
  fc_kernel<<<dim3(4, BB), dim3(256), 0, stream>>>(hf, fcW, fcb, out);
}

// Round 5
// 984.447 us; speedup vs baseline: 2.8837x; 1.3408x over previous
//
#include <hip/hip_runtime.h>
#include <stdint.h>

#define BB 64
#define TT 512
#define DD 256
#define HH 512
#define NG 2048
#define BT (BB*TT)
#define NCLS 1000
#define MAXS 16

typedef _Float16 f16;
typedef _Float16 f16x2 __attribute__((ext_vector_type(2)));
typedef _Float16 f16x4 __attribute__((ext_vector_type(4)));
typedef _Float16 f16x8 __attribute__((ext_vector_type(8)));
typedef float f32x4 __attribute__((ext_vector_type(4)));

// bucket list offsets: OFF[s] = 64 * sum_{s'<s} ceil(512/(s'+1)); capacity 111168
__device__ const int d_OFF[MAXS] = {0,32768,49152,60096,68288,74880,80384,85120,
                                    89216,92864,96192,99200,101952,104512,106880,109120};

__device__ __forceinline__ float sigf(float x) { return 1.0f / (1.0f + __expf(-x)); }
__device__ __forceinline__ float tanh_(float x) {
  float e = __expf(-2.0f * fabsf(x));
  float r = (1.0f - e) / (1.0f + e);
  return copysignf(r, x);
}
__device__ __forceinline__ f32x4 mfma16(f16x8 a, f16x8 b, f32x4 c) {
  return __builtin_amdgcn_mfma_f32_16x16x32_f16(a, b, c, 0, 0, 0);
}
__device__ __forceinline__ void gload16(const void* g, void* l) {
  __builtin_amdgcn_global_load_lds((const __attribute__((address_space(1))) void*)g,
                                   (__attribute__((address_space(3))) void*)l, 16, 0, 0);
}

// ---------------- x cast f32 -> f16 (vectorized) ----------------
__global__ __launch_bounds__(256) void cast_f16(const float* __restrict__ s, f16* __restrict__ d, int n4) {
  int i = blockIdx.x * 256 + threadIdx.x;
  int stride = gridDim.x * 256;
  for (; i < n4; i += stride) {
    float4 v = ((const float4*)s)[i];
    f16x4 o = { (f16)v.x, (f16)v.y, (f16)v.z, (f16)v.w };
    ((f16x4*)d)[i] = o;
  }
}

// ---------------- fused weight casts + bias adds (one launch) ----------------
#define C0 (NG*DD/4)
#define C1 (C0 + NG*HH/4)
#define C2 (C1 + NG*HH/4)
#define C3 (C2 + NG*HH/4)
__global__ __launch_bounds__(256) void prep_weights(
    const float* __restrict__ Wih0, const float* __restrict__ Whh0,
    const float* __restrict__ Wih1, const float* __restrict__ Whh1,
    const float* __restrict__ bih0, const float* __restrict__ bhh0,
    const float* __restrict__ bih1, const float* __restrict__ bhh1,
    f16* __restrict__ W16ih0, f16* __restrict__ W16hh0,
    f16* __restrict__ W16ih1, f16* __restrict__ W16hh1,
    float* __restrict__ bias0, float* __restrict__ bias1) {
  int gi = blockIdx.x * 256 + threadIdx.x;
  for (int i = gi; i < C3; i += gridDim.x * 256) {
    const float* s; f16* d; int o;
    if (i < C0)      { s = Wih0; d = W16ih0; o = i; }
    else if (i < C1) { s = Whh0; d = W16hh0; o = i - C0; }
    else if (i < C2) { s = Wih1; d = W16ih1; o = i - C1; }
    else             { s = Whh1; d = W16hh1; o = i - C2; }
    float4 v = ((const float4*)s)[o];
    f16x4 x = { (f16)v.x, (f16)v.y, (f16)v.z, (f16)v.w };
    ((f16x4*)d)[o] = x;
  }
  if (gi < NG/2) {
    int j = gi * 2;
    bias0[j]   = bih0[j]   + bhh0[j];
    bias0[j+1] = bih0[j+1] + bhh0[j+1];
    bias1[j]   = bih1[j]   + bhh1[j];
    bias1[j+1] = bih1[j+1] + bhh1[j+1];
  }
}

// ---------------- segment bucket lists: LDS-aggregated, padded counters ----------------
__global__ __launch_bounds__(512) void build_lists(const float* __restrict__ mask,
    int* __restrict__ counts, int* __restrict__ lists,
    int* __restrict__ tailcnt, int* __restrict__ taillist) {
  int b = blockIdx.x, t = threadIdx.x;
  __shared__ float sm[512];
  __shared__ int lcnt[MAXS], lbase[MAXS];
  sm[t] = mask[b*TT + t];
  if (t < MAXS) lcnt[t] = 0;
  __syncthreads();
  int run = 0;
  for (int j = 1; j <= MAXS; ++j) {
    if (t - j < 0) break;
    if (sm[t - j] != 0.0f) run++; else break;
  }
  bool tail = (run >= MAXS);
  int slot = -1;
  if (!tail) slot = atomicAdd(&lcnt[run], 1);      // LDS atomic (block-local)
  __syncthreads();
  if (t < MAXS) lbase[t] = atomicAdd(&counts[t*32], lcnt[t]);  // 1 per (block,bucket), line-padded
  __syncthreads();
  if (!tail) lists[d_OFF[run] + lbase[run] + slot] = b*TT + t;
  // ordered (by t) per-batch list of tail positions via block scan
  unsigned long long bal = __ballot(tail);
  int lane = t & 63, w = t >> 6;
  int wpre = __popcll(bal & ((1ull << lane) - 1ull));
  __shared__ int wsum[8];
  if (lane == 0) wsum[w] = __popcll(bal);
  __syncthreads();
  int base = 0;
  for (int i = 0; i < w; ++i) base += wsum[i];
  if (tail) taillist[b*TT + base + wpre] = t;
  if (t == 0) {
    int tot = 0;
    for (int i = 0; i < 8; ++i) tot += wsum[i];
    tailcnt[b] = tot;
  }
}

// ---------------- projection GEMM: C[M][2048] = A[M][K] @ W[2048][K]^T + bias ----------------
__global__ __launch_bounds__(256) void proj_gemm(const f16* __restrict__ A,
    const f16* __restrict__ W, const float* __restrict__ bias,
    f16* __restrict__ C, int K) {
  __shared__ __align__(16) f16 smem[128*128];
  f16* As = smem;
  f16* Bs = smem + 128*64;
  const int nwg = gridDim.x;
  const int cpx = nwg >> 3;
  const int b0i = blockIdx.x;
  const int swz = (b0i & 7) * cpx + (b0i >> 3);
  const int m0 = (swz >> 4) * 128;
  const int n0 = (swz & 15) * 128;
  const int tid = threadIdx.x;
  const int lane = tid & 63;
  const int w = tid >> 6;
  const int srg = lane >> 3;
  const int scol = lane & 7;
  f32x4 acc[4][4] = {};
  for (int k0 = 0; k0 < K; k0 += 64) {
#pragma unroll
    for (int i = 0; i < 4; ++i) {
      int r0 = (i*4 + w) * 8;
      int row = r0 + srg;
      int cg = scol ^ (row & 7);
      gload16(A + (size_t)(m0 + row)*K + k0 + cg*8, As + r0*64);
      gload16(W + (size_t)(n0 + row)*K + k0 + cg*8, Bs + r0*64);
    }
    __syncthreads();
    {
      const int wm = (w >> 1) * 64;
      const int wn = (w & 1) * 64;
      const int cl = lane & 15;
      const int kq = lane >> 4;
#pragma unroll
      for (int ks = 0; ks < 2; ++ks) {
        int kc = ks*4 + kq;
        f16x8 af[4], bf[4];
#pragma unroll
        for (int mi = 0; mi < 4; ++mi) {
          int row = wm + mi*16 + cl;
          af[mi] = *(const f16x8*)(As + row*64 + ((kc ^ (row & 7)) * 8));
        }
#pragma unroll
        for (int ni = 0; ni < 4; ++ni) {
          int row = wn + ni*16 + cl;
          bf[ni] = *(const f16x8*)(Bs + row*64 + ((kc ^ (row & 7)) * 8));
        }
#pragma unroll
        for (int mi = 0; mi < 4; ++mi)
#pragma unroll
          for (int ni = 0; ni < 4; ++ni)
            acc[mi][ni] = mfma16(af[mi], bf[ni], acc[mi][ni]);
      }
    }
    __syncthreads();
  }
  {
    const int wm = (w >> 1) * 64;
    const int wn = (w & 1) * 64;
    const int cl = lane & 15;
    const int rq = lane >> 4;
#pragma unroll
    for (int ni = 0; ni < 4; ++ni) {
      int col = wn + ni*16 + cl;
      float bb = bias[n0 + col];
#pragma unroll
      for (int mi = 0; mi < 4; ++mi)
#pragma unroll
        for (int r = 0; r < 4; ++r)
          smem[(wm + mi*16 + rq*4 + r)*128 + col] = (f16)(acc[mi][ni][r] + bb);
    }
  }
  __syncthreads();
#pragma unroll
  for (int p = 0; p < 8; ++p) {
    int row = p*16 + (tid >> 4);
    int ch = tid & 15;
    f16x8 v = *(const f16x8*)(smem + row*128 + ch*8);
    *(f16x8*)(C + (size_t)(m0 + row)*NG + n0 + ch*8) = v;
  }
}

// ---------------- bucket 0: segment starts (h_prev = c_prev = 0), 4 rows/block ----------------
__global__ __launch_bounds__(512) void lstm_step0(const f16* __restrict__ G,
    f16* __restrict__ HS, f16* __restrict__ CS, const float* __restrict__ mask,
    const int* __restrict__ counts, const int* __restrict__ lists) {
  int cnt = counts[0];
  int i = blockIdx.x * 4 + (threadIdx.x >> 7);
  if (i >= cnt) return;
  int row = lists[i];
  int j4 = (threadIdx.x & 127) * 4;
  size_t gb = (size_t)row * NG;
  f16x4 vi = *(const f16x4*)(G + gb + j4);
  f16x4 vg = *(const f16x4*)(G + gb + 1024 + j4);
  f16x4 vo = *(const f16x4*)(G + gb + 1536 + j4);
  float m = mask[row];
  f16x4 hv, cv;
#pragma unroll
  for (int e = 0; e < 4; ++e) {
    float c = sigf((float)vi[e]) * tanh_((float)vg[e]);
    float h = sigf((float)vo[e]) * tanh_(c);
    hv[e] = (f16)(h*m); cv[e] = (f16)(c*m);
  }
  *(f16x4*)(HS + (size_t)row*HH + j4) = hv;
  *(f16x4*)(CS + (size_t)row*HH + j4) = cv;
}

// ---------------- bucket s (1..4): tiled MFMA step, unit grid-stride ----------------
// unit = (128-row chunk) x (64-j chunk); 8 waves = 2 row-groups x 4 j-groups
__global__ __launch_bounds__(512) void lstm_step(const f16* __restrict__ Wh,
    const f16* __restrict__ G, f16* __restrict__ HS, f16* __restrict__ CS,
    const float* __restrict__ mask, const int* __restrict__ counts,
    const int* __restrict__ lists, int s) {
  const int cnt = counts[s*32];
  if (cnt == 0) return;
  const int units = ((cnt + 127) >> 7) * 8;
  const int* lst = lists + d_OFF[s];
  const int tid = threadIdx.x;
  const int lane = tid & 63;
  const int w = tid >> 6;
  __shared__ __align__(16) f16 As[128*64];
  __shared__ __align__(16) f16 Bs[256*64];
  __shared__ int ridx[128];
  __shared__ float rmk[128];
  const int rg = w >> 2;
  const int jg = w & 3;
  const int cl = lane & 15;
  const int kq = lane >> 4;

  for (int u = blockIdx.x; u < units; u += gridDim.x) {
    const int mbase = (u >> 3) * 128;
    const int j0 = (u & 7) * 64;
    if (tid < 128) {
      int i = mbase + tid;
      int r = (i < cnt) ? lst[i] : -1;
      ridx[tid] = r;
      rmk[tid] = (r >= 0) ? mask[r] : 0.0f;
    }
    __syncthreads();

    const f16* asrc[2];
#pragma unroll
    for (int p = 0; p < 2; ++p) {
      int cid = tid + p*512;
      int r = cid >> 3, c = cid & 7;
      int cs = c ^ (r & 7);
      int rr = ridx[r];
      int sr = (rr >= 1 ? rr : 1) - 1;
      asrc[p] = HS + (size_t)sr*HH + cs*8;
    }
    const f16* bsrc[4];
#pragma unroll
    for (int p = 0; p < 4; ++p) {
      int cid = tid + p*512;
      int grow = cid >> 3, c = cid & 7;
      int cs = c ^ (grow & 7);
      int wrow = (grow >> 6)*512 + j0 + (grow & 63);
      bsrc[p] = Wh + (size_t)wrow*HH + cs*8;
    }

    f32x4 acc[4][4] = {};
    for (int k0 = 0; k0 < HH; k0 += 64) {
#pragma unroll
      for (int p = 0; p < 2; ++p)
        gload16(asrc[p] + k0, As + (tid + p*512)*8);
#pragma unroll
      for (int p = 0; p < 4; ++p)
        gload16(bsrc[p] + k0, Bs + (tid + p*512)*8);
      __syncthreads();
#pragma unroll
      for (int ks = 0; ks < 2; ++ks) {
        int kc = ks*4 + kq;
        f16x8 af[4], bf[4];
#pragma unroll
        for (int mi = 0; mi < 4; ++mi) {
          int row = rg*64 + mi*16 + cl;
          af[mi] = *(const f16x8*)(As + row*64 + ((kc ^ (row & 7))*8));
        }
#pragma unroll
        for (int g = 0; g < 4; ++g) {
          int brow = g*64 + jg*16 + cl;
          bf[g] = *(const f16x8*)(Bs + brow*64 + ((kc ^ (brow & 7))*8));
        }
#pragma unroll
        for (int mi = 0; mi < 4; ++mi)
#pragma unroll
          for (int g = 0; g < 4; ++g)
            acc[mi][g] = mfma16(af[mi], bf[g], acc[mi][g]);
      }
      __syncthreads();
    }

    const int j = j0 + jg*16 + cl;
#pragma unroll
    for (int mi = 0; mi < 4; ++mi)
#pragma unroll
      for (int r = 0; r < 4; ++r) {
        int slot = rg*64 + mi*16 + kq*4 + r;
        int row = ridx[slot];
        if (row >= 0) {
          size_t gb = (size_t)row * NG;
          float gi = acc[mi][0][r] + (float)G[gb + j];
          float gf = acc[mi][1][r] + (float)G[gb + 512 + j];
          float gg = acc[mi][2][r] + (float)G[gb + 1024 + j];
          float go = acc[mi][3][r] + (float)G[gb + 1536 + j];
          float cp = (float)CS[(size_t)(row - 1)*HH + j];
          float c = sigf(gf)*cp + sigf(gi)*tanh_(gg);
          float h = sigf(go)*tanh_(c);
          float m = rmk[slot];
          HS[(size_t)row*HH + j] = (f16)(h*m);
          CS[(size_t)row*HH + j] = (f16)(c*m);
        }
      }
    __syncthreads();   // protect ridx/rmk before next unit
  }
}

// ---------------- bucket s (5..15): THIN tiled MFMA step (small counts) ----------------
// unit = (128-row chunk) x (16-j chunk); 8 waves each own 16 rows; B per unit = 64KB
__global__ __launch_bounds__(512) void lstm_step_thin(const f16* __restrict__ Wh,
    const f16* __restrict__ G, f16* __restrict__ HS, f16* __restrict__ CS,
    const float* __restrict__ mask, const int* __restrict__ counts,
    const int* __restrict__ lists, int s) {
  const int cnt = counts[s*32];
  if (cnt == 0) return;
  const int units = ((cnt + 127) >> 7) * 32;
  const int* lst = lists + d_OFF[s];
  const int tid = threadIdx.x;
  const int lane = tid & 63;
  const int w = tid >> 6;
  __shared__ __align__(16) f16 As[128*64];   // 16KB
  __shared__ __align__(16) f16 Bs[64*64];    // 8KB: grow = gate*16 + jj
  __shared__ int ridx[128];
  __shared__ float rmk[128];
  const int cl = lane & 15;
  const int kq = lane >> 4;
  const int rbase = w * 16;

  for (int u = blockIdx.x; u < units; u += gridDim.x) {
    const int mbase = (u >> 5) * 128;
    const int j0 = (u & 31) * 16;
    if (tid < 128) {
      int i = mbase + tid;
      int r = (i < cnt) ? lst[i] : -1;
      ridx[tid] = r;
      rmk[tid] = (r >= 0) ? mask[r] : 0.0f;
    }
    __syncthreads();

    const f16* asrc[2];
#pragma unroll
    for (int p = 0; p < 2; ++p) {
      int cid = tid + p*512;
      int r = cid >> 3, c = cid & 7;
      int cs = c ^ (r & 7);
      int rr = ridx[r];
      int sr = (rr >= 1 ? rr : 1) - 1;
      asrc[p] = HS + (size_t)sr*HH + cs*8;
    }
    const f16* bsrc;
    {
      int grow = tid >> 3, c = tid & 7;
      int cs = c ^ (grow & 7);
      int wrow = (grow >> 4)*512 + j0 + (grow & 15);
      bsrc = Wh + (size_t)wrow*HH + cs*8;
    }

    f32x4 acc[4] = {};
    for (int k0 = 0; k0 < HH; k0 += 64) {
#pragma unroll
      for (int p = 0; p < 2; ++p)
        gload16(asrc[p] + k0, As + (tid + p*512)*8);
      gload16(bsrc + k0, Bs + tid*8);
      __syncthreads();
#pragma unroll
      for (int ks = 0; ks < 2; ++ks) {
        int kc = ks*4 + kq;
        int arow = rbase + cl;
        f16x8 af = *(const f16x8*)(As + arow*64 + ((kc ^ (arow & 7))*8));
        f16x8 bf[4];
#pragma unroll
        for (int g = 0; g < 4; ++g) {
          int brow = g*16 + cl;
          bf[g] = *(const f16x8*)(Bs + brow*64 + ((kc ^ (brow & 7))*8));
        }
#pragma unroll
        for (int g = 0; g < 4; ++g)
          acc[g] = mfma16(af, bf[g], acc[g]);
      }
      __syncthreads();
    }

    const int j = j0 + cl;
#pragma unroll
    for (int r = 0; r < 4; ++r) {
      int slot = rbase + kq*4 + r;
      int row = ridx[slot];
      if (row >= 0) {
        size_t gb = (size_t)row * NG;
        float gi = acc[0][r] + (float)G[gb + j];
        float gf = acc[1][r] + (float)G[gb + 512 + j];
        float gg = acc[2][r] + (float)G[gb + 1024 + j];
        float go = acc[3][r] + (float)G[gb + 1536 + j];
        float cp = (float)CS[(size_t)(row - 1)*HH + j];
        float c = sigf(gf)*cp + sigf(gi)*tanh_(gg);
        float h = sigf(go)*tanh_(c);
        float m = rmk[slot];
        HS[(size_t)row*HH + j] = (f16)(h*m);
        CS[(size_t)row*HH + j] = (f16)(c*m);
      }
    }
    __syncthreads();
  }
}

// ---------------- tail: run >= 16, sequential per batch (expected empty) ----------------
__global__ __launch_bounds__(512) void lstm_tail(const f16* __restrict__ Wh,
    const f16* __restrict__ G, f16* __restrict__ HS, f16* __restrict__ CS,
    const float* __restrict__ mask, const int* __restrict__ tailcnt,
    const int* __restrict__ taillist) {
  int b = blockIdx.x;
  int n = tailcnt[b];
  if (n == 0) return;
  int tid = threadIdx.x;
  __shared__ __align__(4) f16 hsh[HH];
  __shared__ float gsh[NG];
  for (int i = 0; i < n; ++i) {
    int t = taillist[b*TT + i];
    size_t row = (size_t)b*TT + t;
    if (tid < 256)
      ((uint32_t*)hsh)[tid] = ((const uint32_t*)(HS + (row - 1)*HH))[tid];
    __syncthreads();
#pragma unroll
    for (int rep = 0; rep < 4; ++rep) {
      int o = tid + rep*512;
      float a = (float)G[row*NG + o];
      const f16x8* wr = (const f16x8*)(Wh + (size_t)o*HH);
      const f16x2* hp = (const f16x2*)hsh;
#pragma unroll 4
      for (int k8 = 0; k8 < 64; ++k8) {
        f16x8 wv = wr[k8];
        f16x2 p0 = {wv[0], wv[1]}, p1 = {wv[2], wv[3]}, p2 = {wv[4], wv[5]}, p3 = {wv[6], wv[7]};
        a = __builtin_amdgcn_fdot2(p0, hp[k8*4+0], a, false);
        a = __builtin_amdgcn_fdot2(p1, hp[k8*4+1], a, false);
        a = __builtin_amdgcn_fdot2(p2, hp[k8*4+2], a, false);
        a = __builtin_amdgcn_fdot2(p3, hp[k8*4+3], a, false);
      }
      gsh[o] = a;
    }
    __syncthreads();
    {
      float cp = (float)CS[(row - 1)*HH + tid];
      float c = sigf(gsh[512 + tid])*cp + sigf(gsh[tid])*tanh_(gsh[1024 + tid]);
      float h = sigf(gsh[1536 + tid])*tanh_(c);
      float m = mask[row];
      HS[row*HH + tid] = (f16)(h*m);
      CS[row*HH + tid] = (f16)(c*m);
    }
    __syncthreads();
  }
}

// ---------------- relu + layernorm, wave-per-row ----------------
__global__ __launch_bounds__(512) void ln_relu(const f16* __restrict__ in,
    const float* __restrict__ g, const float* __restrict__ be,
    f16* __restrict__ out) {
  int lane = threadIdx.x & 63, w = threadIdx.x >> 6;
  int row = blockIdx.x * 8 + w;
  f16x8 hv = *(const f16x8*)(in + (size_t)row*HH + lane*8);
  float xv[8]; float s1 = 0.f, s2 = 0.f;
#pragma unroll
  for (int e = 0; e < 8; ++e) { float x = fmaxf((float)hv[e], 0.f); xv[e] = x; s1 += x; s2 += x*x; }
#pragma unroll
  for (int o = 1; o < 64; o <<= 1) { s1 += __shfl_xor(s1, o); s2 += __shfl_xor(s2, o); }
  float mu = s1 * (1.0f/512.0f);
  float var = s2 * (1.0f/512.0f) - mu*mu;
  float rs = rsqrtf(var + 1e-5f);
  f16x8 ov;
#pragma unroll
  for (int e = 0; e < 8; ++e) ov[e] = (f16)((xv[e] - mu)*rs*g[lane*8+e] + be[lane*8+e]);
  *(f16x8*)(out + (size_t)row*HH + lane*8) = ov;
}

// layernorm of the final (t=T-1) hidden state, f32 output
__global__ __launch_bounds__(512) void ln_last(const f16* __restrict__ HS,
    const float* __restrict__ g, const float* __restrict__ be, float* __restrict__ out) {
  int b = blockIdx.x;
  int j = threadIdx.x;
  float x = fmaxf((float)HS[((size_t)b*TT + (TT-1))*HH + j], 0.0f);
  float s1 = x, s2 = x*x;
  for (int o = 32; o > 0; o >>= 1) { s1 += __shfl_down(s1, o); s2 += __shfl_down(s2, o); }
  __shared__ float a1[8], a2[8];
  int w = j >> 6;
  if ((j & 63) == 0) { a1[w] = s1; a2[w] = s2; }
  __syncthreads();
  if (j == 0) {
    float t1 = 0.f, t2 = 0.f;
    for (int i = 0; i < 8; ++i) { t1 += a1[i]; t2 += a2[i]; }
    a1[0] = t1; a2[0] = t2;
  }
  __syncthreads();
  float mu = a1[0] * (1.0f/512.0f);
  float var = a2[0] * (1.0f/512.0f) - mu*mu;
  float y = (x - mu) * rsqrtf(var + 1e-5f) * g[j] + be[j];
  out[b*HH + j] = y;
}

// ---------------- final classifier: out[64][1000] = hf @ fcW^T + fcb ----------------
__global__ __launch_bounds__(256) void fc_kernel(const float* __restrict__ hf,
    const float* __restrict__ W, const float* __restrict__ bias, float* __restrict__ out) {
  int b = blockIdx.y;
  int c = blockIdx.x * 256 + threadIdx.x;
  __shared__ float hsh[512];
  hsh[threadIdx.x] = hf[b*HH + threadIdx.x];
  hsh[threadIdx.x + 256] = hf[b*HH + 256 + threadIdx.x];
  __syncthreads();
  if (c < NCLS) {
    const float4* wr = (const float4*)(W + (size_t)c*HH);
    float acc = bias[c];
#pragma unroll 4
    for (int k4 = 0; k4 < 128; ++k4) {
      float4 wv = wr[k4];
      acc += wv.x*hsh[k4*4] + wv.y*hsh[k4*4+1] + wv.z*hsh[k4*4+2] + wv.w*hsh[k4*4+3];
    }
    out[b*NCLS + c] = acc;
  }
}

extern "C" void kernel_launch(void* const* d_in, const int* in_sizes, int n_in,
                              void* d_out, int out_size, void* d_ws, size_t ws_size,
                              hipStream_t stream) {
  (void)in_sizes; (void)n_in; (void)out_size;
  const float* x    = (const float*)d_in[0];
  const float* mask = (const float*)d_in[1];
  const float* Wih0 = (const float*)d_in[2];
  const float* Whh0 = (const float*)d_in[3];
  const float* bih0 = (const float*)d_in[4];
  const float* bhh0 = (const float*)d_in[5];
  const float* g0   = (const float*)d_in[6];
  const float* be0  = (const float*)d_in[7];
  const float* Wih1 = (const float*)d_in[8];
  const float* Whh1 = (const float*)d_in[9];
  const float* bih1 = (const float*)d_in[10];
  const float* bhh1 = (const float*)d_in[11];
  const float* g1   = (const float*)d_in[12];
  const float* be1  = (const float*)d_in[13];
  const float* fcW  = (const float*)d_in[14];
  const float* fcb  = (const float*)d_in[15];
  float* out = (float*)d_out;

  char* ws = (char*)d_ws;
  size_t off = 0;
  auto alloc = [&](size_t bytes) { size_t o = off; off += (bytes + 255) & ~(size_t)255; return o; };
  f16* G      = (f16*)(ws + alloc((size_t)BT*NG*2));
  f16* HS     = (f16*)(ws + alloc((size_t)BT*HH*2));
  f16* CS     = (f16*)(ws + alloc((size_t)BT*HH*2));
  f16* H0LN   = (f16*)(ws + alloc((size_t)BT*HH*2));
  f16* W16ih0 = (f16*)(ws + alloc((size_t)NG*DD*2));
  f16* W16hh0 = (f16*)(ws + alloc((size_t)NG*HH*2));
  f16* W16ih1 = (f16*)(ws + alloc((size_t)NG*HH*2));
  f16* W16hh1 = (f16*)(ws + alloc((size_t)NG*HH*2));
  float* bias0 = (float*)(ws + alloc(NG*4));
  float* bias1 = (float*)(ws + alloc(NG*4));
  int* counts  = (int*)(ws + alloc(4096));       // counts[s*32], s=0..15 | tailcnt @ +512
  int* tailcnt = counts + 512;
  int* lists   = (int*)(ws + alloc(111168*4));
  int* taillist= (int*)(ws + alloc((size_t)BT*4));
  float* hf    = (float*)(ws + alloc((size_t)BB*HH*4));
  if (ws_size < off) return;

  f16* AX = H0LN;  // x-f16 region, consumed by proj0 before H0LN written

  hipMemsetAsync(counts, 0, 4096, stream);
  cast_f16<<<dim3(512), dim3(256), 0, stream>>>(x, AX, BT*DD/4);
  prep_weights<<<dim3(512), dim3(256), 0, stream>>>(Wih0, Whh0, Wih1, Whh1,
      bih0, bhh0, bih1, bhh1, W16ih0, W16hh0, W16ih1, W16hh1, bias0, bias1);
  build_lists<<<dim3(BB), dim3(512), 0, stream>>>(mask, counts, lists, tailcnt, taillist);

  for (int layer = 0; layer < 2; ++layer) {
    const f16* Wih16 = layer ? W16ih1 : W16ih0;
    const f16* Whh16 = layer ? W16hh1 : W16hh0;
    const float* bias = layer ? bias1 : bias0;
    const f16* Ain = layer ? H0LN : AX;
    int K = layer ? HH : DD;
    proj_gemm<<<dim3((BT/128)*(NG/128)), dim3(256), 0, stream>>>(Ain, Wih16, bias, G, K);
    lstm_step0<<<dim3(BT/4), dim3(512), 0, stream>>>(G, HS, CS, mask, counts, lists);
    for (int s = 1; s < 5; ++s)
      lstm_step<<<dim3(512), dim3(512), 0, stream>>>(Whh16, G, HS, CS, mask, counts, lists, s);
    for (int s = 5; s < MAXS; ++s)
      lstm_step_thin<<<dim3(256), dim3(512), 0, stream>>>(Whh16, G, HS, CS, mask, counts, lists, s);
    lstm_tail<<<dim3(BB), dim3(512), 0, stream>>>(Whh16, G, HS, CS, mask, tailcnt, taillist);
    if (layer == 0)
      ln_relu<<<dim3(BT/8), dim3(512), 0, stream>>>(HS, g0, be0, H0LN);
  }

  ln_last<<<dim3(BB), dim3(512), 0, stream>>>(HS, g1, be1, hf);
  fc_kernel<<<dim3(4, BB), dim3(256), 0, stream>>>(hf, fcW, fcb, out);
}

// Round 6
// 845.319 us; speedup vs baseline: 3.3583x; 1.1646x over previous
//
#include <hip/hip_runtime.h>
#include <stdint.h>

#define BB 64
#define TT 512
#define DD 256
#define HH 512
#define NG 2048
#define BT (BB*TT)
#define NCLS 1000
#define MAXS 16

typedef _Float16 f16;
typedef _Float16 f16x2 __attribute__((ext_vector_type(2)));
typedef _Float16 f16x4 __attribute__((ext_vector_type(4)));
typedef _Float16 f16x8 __attribute__((ext_vector_type(8)));
typedef float f32x4 __attribute__((ext_vector_type(4)));

// bucket list offsets: OFF[s] = 64 * sum_{s'<s} ceil(512/(s'+1)); capacity 111168
__device__ const int d_OFF[MAXS] = {0,32768,49152,60096,68288,74880,80384,85120,
                                    89216,92864,96192,99200,101952,104512,106880,109120};

__device__ __forceinline__ float sigf(float x) { return 1.0f / (1.0f + __expf(-x)); }
__device__ __forceinline__ float tanh_(float x) {
  float e = __expf(-2.0f * fabsf(x));
  float r = (1.0f - e) / (1.0f + e);
  return copysignf(r, x);
}
__device__ __forceinline__ f32x4 mfma16(f16x8 a, f16x8 b, f32x4 c) {
  return __builtin_amdgcn_mfma_f32_16x16x32_f16(a, b, c, 0, 0, 0);
}
__device__ __forceinline__ void gload16(const void* g, void* l) {
  __builtin_amdgcn_global_load_lds((const __attribute__((address_space(1))) void*)g,
                                   (__attribute__((address_space(3))) void*)l, 16, 0, 0);
}

// ---------------- fused: weight casts + bias adds + x cast (one launch) ----------------
#define C0 (NG*DD/4)
#define C1 (C0 + NG*HH/4)
#define C2 (C1 + NG*HH/4)
#define C3 (C2 + NG*HH/4)
#define CX (C3 + BT*DD/4)
__global__ __launch_bounds__(256) void prep_weights(
    const float* __restrict__ Wih0, const float* __restrict__ Whh0,
    const float* __restrict__ Wih1, const float* __restrict__ Whh1,
    const float* __restrict__ x,
    const float* __restrict__ bih0, const float* __restrict__ bhh0,
    const float* __restrict__ bih1, const float* __restrict__ bhh1,
    f16* __restrict__ W16ih0, f16* __restrict__ W16hh0,
    f16* __restrict__ W16ih1, f16* __restrict__ W16hh1,
    f16* __restrict__ AX,
    float* __restrict__ bias0, float* __restrict__ bias1) {
  int gi = blockIdx.x * 256 + threadIdx.x;
  for (int i = gi; i < CX; i += gridDim.x * 256) {
    const float* s; f16* d; int o;
    if (i < C0)      { s = Wih0; d = W16ih0; o = i; }
    else if (i < C1) { s = Whh0; d = W16hh0; o = i - C0; }
    else if (i < C2) { s = Wih1; d = W16ih1; o = i - C1; }
    else if (i < C3) { s = Whh1; d = W16hh1; o = i - C2; }
    else             { s = x;    d = AX;     o = i - C3; }
    float4 v = ((const float4*)s)[o];
    f16x4 h = { (f16)v.x, (f16)v.y, (f16)v.z, (f16)v.w };
    ((f16x4*)d)[o] = h;
  }
  if (gi < NG/2) {
    int j = gi * 2;
    bias0[j]   = bih0[j]   + bhh0[j];
    bias0[j+1] = bih0[j+1] + bhh0[j+1];
    bias1[j]   = bih1[j]   + bhh1[j];
    bias1[j+1] = bih1[j+1] + bhh1[j+1];
  }
}

// ---------------- segment bucket lists: LDS-aggregated, padded counters ----------------
__global__ __launch_bounds__(512) void build_lists(const float* __restrict__ mask,
    int* __restrict__ counts, int* __restrict__ lists,
    int* __restrict__ tailcnt, int* __restrict__ taillist) {
  int b = blockIdx.x, t = threadIdx.x;
  __shared__ float sm[512];
  __shared__ int lcnt[MAXS], lbase[MAXS];
  sm[t] = mask[b*TT + t];
  if (t < MAXS) lcnt[t] = 0;
  __syncthreads();
  int run = 0;
  for (int j = 1; j <= MAXS; ++j) {
    if (t - j < 0) break;
    if (sm[t - j] != 0.0f) run++; else break;
  }
  bool tail = (run >= MAXS);
  int slot = -1;
  if (!tail) slot = atomicAdd(&lcnt[run], 1);      // LDS atomic (block-local)
  __syncthreads();
  if (t < MAXS) lbase[t] = atomicAdd(&counts[t*32], lcnt[t]);  // 1 per (block,bucket)
  __syncthreads();
  if (!tail) lists[d_OFF[run] + lbase[run] + slot] = b*TT + t;
  // ordered (by t) per-batch list of tail positions via block scan
  unsigned long long bal = __ballot(tail);
  int lane = t & 63, w = t >> 6;
  int wpre = __popcll(bal & ((1ull << lane) - 1ull));
  __shared__ int wsum[8];
  if (lane == 0) wsum[w] = __popcll(bal);
  __syncthreads();
  int base = 0;
  for (int i = 0; i < w; ++i) base += wsum[i];
  if (tail) taillist[b*TT + base + wpre] = t;
  if (t == 0) {
    int tot = 0;
    for (int i = 0; i < 8; ++i) tot += wsum[i];
    tailcnt[b] = tot;
  }
}

// ---------------- projection GEMM: C[M][2048] = A[M][K] @ W[2048][K]^T + bias ----------------
__global__ __launch_bounds__(256) void proj_gemm(const f16* __restrict__ A,
    const f16* __restrict__ W, const float* __restrict__ bias,
    f16* __restrict__ C, int K) {
  __shared__ __align__(16) f16 smem[128*128];
  f16* As = smem;
  f16* Bs = smem + 128*64;
  const int nwg = gridDim.x;
  const int cpx = nwg >> 3;
  const int b0i = blockIdx.x;
  const int swz = (b0i & 7) * cpx + (b0i >> 3);
  const int m0 = (swz >> 4) * 128;
  const int n0 = (swz & 15) * 128;
  const int tid = threadIdx.x;
  const int lane = tid & 63;
  const int w = tid >> 6;
  const int srg = lane >> 3;
  const int scol = lane & 7;
  f32x4 acc[4][4] = {};
  for (int k0 = 0; k0 < K; k0 += 64) {
#pragma unroll
    for (int i = 0; i < 4; ++i) {
      int r0 = (i*4 + w) * 8;
      int row = r0 + srg;
      int cg = scol ^ (row & 7);
      gload16(A + (size_t)(m0 + row)*K + k0 + cg*8, As + r0*64);
      gload16(W + (size_t)(n0 + row)*K + k0 + cg*8, Bs + r0*64);
    }
    __syncthreads();
    {
      const int wm = (w >> 1) * 64;
      const int wn = (w & 1) * 64;
      const int cl = lane & 15;
      const int kq = lane >> 4;
#pragma unroll
      for (int ks = 0; ks < 2; ++ks) {
        int kc = ks*4 + kq;
        f16x8 af[4], bf[4];
#pragma unroll
        for (int mi = 0; mi < 4; ++mi) {
          int row = wm + mi*16 + cl;
          af[mi] = *(const f16x8*)(As + row*64 + ((kc ^ (row & 7)) * 8));
        }
#pragma unroll
        for (int ni = 0; ni < 4; ++ni) {
          int row = wn + ni*16 + cl;
          bf[ni] = *(const f16x8*)(Bs + row*64 + ((kc ^ (row & 7)) * 8));
        }
#pragma unroll
        for (int mi = 0; mi < 4; ++mi)
#pragma unroll
          for (int ni = 0; ni < 4; ++ni)
            acc[mi][ni] = mfma16(af[mi], bf[ni], acc[mi][ni]);
      }
    }
    __syncthreads();
  }
  {
    const int wm = (w >> 1) * 64;
    const int wn = (w & 1) * 64;
    const int cl = lane & 15;
    const int rq = lane >> 4;
#pragma unroll
    for (int ni = 0; ni < 4; ++ni) {
      int col = wn + ni*16 + cl;
      float bb = bias[n0 + col];
#pragma unroll
      for (int mi = 0; mi < 4; ++mi)
#pragma unroll
        for (int r = 0; r < 4; ++r)
          smem[(wm + mi*16 + rq*4 + r)*128 + col] = (f16)(acc[mi][ni][r] + bb);
    }
  }
  __syncthreads();
#pragma unroll
  for (int p = 0; p < 8; ++p) {
    int row = p*16 + (tid >> 4);
    int ch = tid & 15;
    f16x8 v = *(const f16x8*)(smem + row*128 + ch*8);
    *(f16x8*)(C + (size_t)(m0 + row)*NG + n0 + ch*8) = v;
  }
}

// ---------------- bucket 0: segment starts (h_prev = c_prev = 0), 4 rows/block ----------------
__global__ __launch_bounds__(512) void lstm_step0(const f16* __restrict__ G,
    f16* __restrict__ HS, f16* __restrict__ CS, const float* __restrict__ mask,
    const int* __restrict__ counts, const int* __restrict__ lists) {
  int cnt = counts[0];
  int i = blockIdx.x * 4 + (threadIdx.x >> 7);
  if (i >= cnt) return;
  int row = lists[i];
  int j4 = (threadIdx.x & 127) * 4;
  size_t gb = (size_t)row * NG;
  f16x4 vi = *(const f16x4*)(G + gb + j4);
  f16x4 vg = *(const f16x4*)(G + gb + 1024 + j4);
  f16x4 vo = *(const f16x4*)(G + gb + 1536 + j4);
  float m = mask[row];
  f16x4 hv, cv;
#pragma unroll
  for (int e = 0; e < 4; ++e) {
    float c = sigf((float)vi[e]) * tanh_((float)vg[e]);
    float h = sigf((float)vo[e]) * tanh_(c);
    hv[e] = (f16)(h*m); cv[e] = (f16)(c*m);
  }
  *(f16x4*)(HS + (size_t)row*HH + j4) = hv;
  *(f16x4*)(CS + (size_t)row*HH + j4) = cv;
}

// ---------------- bucket s (1..4): tiled MFMA step, unit grid-stride ----------------
__global__ __launch_bounds__(512) void lstm_step(const f16* __restrict__ Wh,
    const f16* __restrict__ G, f16* __restrict__ HS, f16* __restrict__ CS,
    const float* __restrict__ mask, const int* __restrict__ counts,
    const int* __restrict__ lists, int s) {
  const int cnt = counts[s*32];
  if (cnt == 0) return;
  const int units = ((cnt + 127) >> 7) * 8;
  const int* lst = lists + d_OFF[s];
  const int tid = threadIdx.x;
  const int lane = tid & 63;
  const int w = tid >> 6;
  __shared__ __align__(16) f16 As[128*64];
  __shared__ __align__(16) f16 Bs[256*64];
  __shared__ int ridx[128];
  __shared__ float rmk[128];
  const int rg = w >> 2;
  const int jg = w & 3;
  const int cl = lane & 15;
  const int kq = lane >> 4;

  for (int u = blockIdx.x; u < units; u += gridDim.x) {
    const int mbase = (u >> 3) * 128;
    const int j0 = (u & 7) * 64;
    if (tid < 128) {
      int i = mbase + tid;
      int r = (i < cnt) ? lst[i] : -1;
      ridx[tid] = r;
      rmk[tid] = (r >= 0) ? mask[r] : 0.0f;
    }
    __syncthreads();

    const f16* asrc[2];
#pragma unroll
    for (int p = 0; p < 2; ++p) {
      int cid = tid + p*512;
      int r = cid >> 3, c = cid & 7;
      int cs = c ^ (r & 7);
      int rr = ridx[r];
      int sr = (rr >= 1 ? rr : 1) - 1;
      asrc[p] = HS + (size_t)sr*HH + cs*8;
    }
    const f16* bsrc[4];
#pragma unroll
    for (int p = 0; p < 4; ++p) {
      int cid = tid + p*512;
      int grow = cid >> 3, c = cid & 7;
      int cs = c ^ (grow & 7);
      int wrow = (grow >> 6)*512 + j0 + (grow & 63);
      bsrc[p] = Wh + (size_t)wrow*HH + cs*8;
    }

    f32x4 acc[4][4] = {};
    for (int k0 = 0; k0 < HH; k0 += 64) {
#pragma unroll
      for (int p = 0; p < 2; ++p)
        gload16(asrc[p] + k0, As + (tid + p*512)*8);
#pragma unroll
      for (int p = 0; p < 4; ++p)
        gload16(bsrc[p] + k0, Bs + (tid + p*512)*8);
      __syncthreads();
#pragma unroll
      for (int ks = 0; ks < 2; ++ks) {
        int kc = ks*4 + kq;
        f16x8 af[4], bf[4];
#pragma unroll
        for (int mi = 0; mi < 4; ++mi) {
          int row = rg*64 + mi*16 + cl;
          af[mi] = *(const f16x8*)(As + row*64 + ((kc ^ (row & 7))*8));
        }
#pragma unroll
        for (int g = 0; g < 4; ++g) {
          int brow = g*64 + jg*16 + cl;
          bf[g] = *(const f16x8*)(Bs + brow*64 + ((kc ^ (brow & 7))*8));
        }
#pragma unroll
        for (int mi = 0; mi < 4; ++mi)
#pragma unroll
          for (int g = 0; g < 4; ++g)
            acc[mi][g] = mfma16(af[mi], bf[g], acc[mi][g]);
      }
      __syncthreads();
    }

    const int j = j0 + jg*16 + cl;
#pragma unroll
    for (int mi = 0; mi < 4; ++mi)
#pragma unroll
      for (int r = 0; r < 4; ++r) {
        int slot = rg*64 + mi*16 + kq*4 + r;
        int row = ridx[slot];
        if (row >= 0) {
          size_t gb = (size_t)row * NG;
          float gi = acc[mi][0][r] + (float)G[gb + j];
          float gf = acc[mi][1][r] + (float)G[gb + 512 + j];
          float gg = acc[mi][2][r] + (float)G[gb + 1024 + j];
          float go = acc[mi][3][r] + (float)G[gb + 1536 + j];
          float cp = (float)CS[(size_t)(row - 1)*HH + j];
          float c = sigf(gf)*cp + sigf(gi)*tanh_(gg);
          float h = sigf(go)*tanh_(c);
          float m = rmk[slot];
          HS[(size_t)row*HH + j] = (f16)(h*m);
          CS[(size_t)row*HH + j] = (f16)(c*m);
        }
      }
    __syncthreads();   // protect ridx/rmk before next unit
  }
}

// ---------------- bucket s (5..15): THIN tiled MFMA step (small counts) ----------------
__global__ __launch_bounds__(512) void lstm_step_thin(const f16* __restrict__ Wh,
    const f16* __restrict__ G, f16* __restrict__ HS, f16* __restrict__ CS,
    const float* __restrict__ mask, const int* __restrict__ counts,
    const int* __restrict__ lists, int s) {
  const int cnt = counts[s*32];
  if (cnt == 0) return;
  const int units = ((cnt + 127) >> 7) * 32;
  const int* lst = lists + d_OFF[s];
  const int tid = threadIdx.x;
  const int lane = tid & 63;
  const int w = tid >> 6;
  __shared__ __align__(16) f16 As[128*64];   // 16KB
  __shared__ __align__(16) f16 Bs[64*64];    // 8KB: grow = gate*16 + jj
  __shared__ int ridx[128];
  __shared__ float rmk[128];
  const int cl = lane & 15;
  const int kq = lane >> 4;
  const int rbase = w * 16;

  for (int u = blockIdx.x; u < units; u += gridDim.x) {
    const int mbase = (u >> 5) * 128;
    const int j0 = (u & 31) * 16;
    if (tid < 128) {
      int i = mbase + tid;
      int r = (i < cnt) ? lst[i] : -1;
      ridx[tid] = r;
      rmk[tid] = (r >= 0) ? mask[r] : 0.0f;
    }
    __syncthreads();

    const f16* asrc[2];
#pragma unroll
    for (int p = 0; p < 2; ++p) {
      int cid = tid + p*512;
      int r = cid >> 3, c = cid & 7;
      int cs = c ^ (r & 7);
      int rr = ridx[r];
      int sr = (rr >= 1 ? rr : 1) - 1;
      asrc[p] = HS + (size_t)sr*HH + cs*8;
    }
    const f16* bsrc;
    {
      int grow = tid >> 3, c = tid & 7;
      int cs = c ^ (grow & 7);
      int wrow = (grow >> 4)*512 + j0 + (grow & 15);
      bsrc = Wh + (size_t)wrow*HH + cs*8;
    }

    f32x4 acc[4] = {};
    for (int k0 = 0; k0 < HH; k0 += 64) {
#pragma unroll
      for (int p = 0; p < 2; ++p)
        gload16(asrc[p] + k0, As + (tid + p*512)*8);
      gload16(bsrc + k0, Bs + tid*8);
      __syncthreads();
#pragma unroll
      for (int ks = 0; ks < 2; ++ks) {
        int kc = ks*4 + kq;
        int arow = rbase + cl;
        f16x8 af = *(const f16x8*)(As + arow*64 + ((kc ^ (arow & 7))*8));
        f16x8 bf[4];
#pragma unroll
        for (int g = 0; g < 4; ++g) {
          int brow = g*16 + cl;
          bf[g] = *(const f16x8*)(Bs + brow*64 + ((kc ^ (brow & 7))*8));
        }
#pragma unroll
        for (int g = 0; g < 4; ++g)
          acc[g] = mfma16(af, bf[g], acc[g]);
      }
      __syncthreads();
    }

    const int j = j0 + cl;
#pragma unroll
    for (int r = 0; r < 4; ++r) {
      int slot = rbase + kq*4 + r;
      int row = ridx[slot];
      if (row >= 0) {
        size_t gb = (size_t)row * NG;
        float gi = acc[0][r] + (float)G[gb + j];
        float gf = acc[1][r] + (float)G[gb + 512 + j];
        float gg = acc[2][r] + (float)G[gb + 1024 + j];
        float go = acc[3][r] + (float)G[gb + 1536 + j];
        float cp = (float)CS[(size_t)(row - 1)*HH + j];
        float c = sigf(gf)*cp + sigf(gi)*tanh_(gg);
        float h = sigf(go)*tanh_(c);
        float m = rmk[slot];
        HS[(size_t)row*HH + j] = (f16)(h*m);
        CS[(size_t)row*HH + j] = (f16)(c*m);
      }
    }
    __syncthreads();
  }
}

// ---------------- tail: run >= 16, sequential per batch (rare; coalesced matvec) ----------------
// wave w owns rows [w*256, w*256+256) in batches of 8; lane covers k-slice (lane&7)*8 + 64*kk
__global__ __launch_bounds__(512) void lstm_tail(const f16* __restrict__ Wh,
    const f16* __restrict__ G, f16* __restrict__ HS, f16* __restrict__ CS,
    const float* __restrict__ mask, const int* __restrict__ tailcnt,
    const int* __restrict__ taillist) {
  int b = blockIdx.x;
  int n = tailcnt[b];
  if (n == 0) return;
  int tid = threadIdx.x, lane = tid & 63, w = tid >> 6;
  const int rl = lane >> 3;        // row within 8-row batch
  const int kb = (lane & 7) * 8;   // k-slice base
  __shared__ __align__(16) f16 hsh[HH];
  __shared__ float gsh[NG];
  for (int i = 0; i < n; ++i) {
    int t = taillist[b*TT + i];
    size_t row = (size_t)b*TT + t;
    if (tid < 256)
      ((uint32_t*)hsh)[tid] = ((const uint32_t*)(HS + (row - 1)*HH))[tid];
    __syncthreads();
    f16x8 hreg[8];
#pragma unroll
    for (int kk = 0; kk < 8; ++kk)
      hreg[kk] = *(const f16x8*)(hsh + kb + kk*64);
#pragma unroll 2
    for (int batch = 0; batch < 32; ++batch) {
      int o = (w*32 + batch)*8 + rl;
      const f16* wrow = Wh + (size_t)o*HH + kb;
      float p = 0.0f;
#pragma unroll
      for (int kk = 0; kk < 8; ++kk) {
        f16x8 wv = *(const f16x8*)(wrow + kk*64);
        f16x2 w0 = {wv[0], wv[1]}, w1 = {wv[2], wv[3]}, w2 = {wv[4], wv[5]}, w3 = {wv[6], wv[7]};
        f16x2 h0 = {hreg[kk][0], hreg[kk][1]}, h1 = {hreg[kk][2], hreg[kk][3]},
              h2 = {hreg[kk][4], hreg[kk][5]}, h3 = {hreg[kk][6], hreg[kk][7]};
        p = __builtin_amdgcn_fdot2(w0, h0, p, false);
        p = __builtin_amdgcn_fdot2(w1, h1, p, false);
        p = __builtin_amdgcn_fdot2(w2, h2, p, false);
        p = __builtin_amdgcn_fdot2(w3, h3, p, false);
      }
      p += __shfl_xor(p, 1);
      p += __shfl_xor(p, 2);
      p += __shfl_xor(p, 4);
      if ((lane & 7) == 0) gsh[o] = p + (float)G[row*NG + o];
    }
    __syncthreads();
    {
      float cp = (float)CS[(row - 1)*HH + tid];
      float c = sigf(gsh[512 + tid])*cp + sigf(gsh[tid])*tanh_(gsh[1024 + tid]);
      float h = sigf(gsh[1536 + tid])*tanh_(c);
      float m = mask[row];
      HS[row*HH + tid] = (f16)(h*m);
      CS[row*HH + tid] = (f16)(c*m);
    }
    __syncthreads();
  }
}

// ---------------- relu + layernorm, wave-per-row ----------------
__global__ __launch_bounds__(512) void ln_relu(const f16* __restrict__ in,
    const float* __restrict__ g, const float* __restrict__ be,
    f16* __restrict__ out) {
  int lane = threadIdx.x & 63, w = threadIdx.x >> 6;
  int row = blockIdx.x * 8 + w;
  f16x8 hv = *(const f16x8*)(in + (size_t)row*HH + lane*8);
  float xv[8]; float s1 = 0.f, s2 = 0.f;
#pragma unroll
  for (int e = 0; e < 8; ++e) { float x = fmaxf((float)hv[e], 0.f); xv[e] = x; s1 += x; s2 += x*x; }
#pragma unroll
  for (int o = 1; o < 64; o <<= 1) { s1 += __shfl_xor(s1, o); s2 += __shfl_xor(s2, o); }
  float mu = s1 * (1.0f/512.0f);
  float var = s2 * (1.0f/512.0f) - mu*mu;
  float rs = rsqrtf(var + 1e-5f);
  f16x8 ov;
#pragma unroll
  for (int e = 0; e < 8; ++e) ov[e] = (f16)((xv[e] - mu)*rs*g[lane*8+e] + be[lane*8+e]);
  *(f16x8*)(out + (size_t)row*HH + lane*8) = ov;
}

// layernorm of the final (t=T-1) hidden state, f32 output
__global__ __launch_bounds__(512) void ln_last(const f16* __restrict__ HS,
    const float* __restrict__ g, const float* __restrict__ be, float* __restrict__ out) {
  int b = blockIdx.x;
  int j = threadIdx.x;
  float x = fmaxf((float)HS[((size_t)b*TT + (TT-1))*HH + j], 0.0f);
  float s1 = x, s2 = x*x;
  for (int o = 32; o > 0; o >>= 1) { s1 += __shfl_down(s1, o); s2 += __shfl_down(s2, o); }
  __shared__ float a1[8], a2[8];
  int w = j >> 6;
  if ((j & 63) == 0) { a1[w] = s1; a2[w] = s2; }
  __syncthreads();
  if (j == 0) {
    float t1 = 0.f, t2 = 0.f;
    for (int i = 0; i < 8; ++i) { t1 += a1[i]; t2 += a2[i]; }
    a1[0] = t1; a2[0] = t2;
  }
  __syncthreads();
  float mu = a1[0] * (1.0f/512.0f);
  float var = a2[0] * (1.0f/512.0f) - mu*mu;
  float y = (x - mu) * rsqrtf(var + 1e-5f) * g[j] + be[j];
  out[b*HH + j] = y;
}

// ---------------- final classifier: out[64][1000] = hf @ fcW^T + fcb ----------------
__global__ __launch_bounds__(256) void fc_kernel(const float* __restrict__ hf,
    const float* __restrict__ W, const float* __restrict__ bias, float* __restrict__ out) {
  int b = blockIdx.y;
  int c = blockIdx.x * 256 + threadIdx.x;
  __shared__ float hsh[512];
  hsh[threadIdx.x] = hf[b*HH + threadIdx.x];
  hsh[threadIdx.x + 256] = hf[b*HH + 256 + threadIdx.x];
  __syncthreads();
  if (c < NCLS) {
    const float4* wr = (const float4*)(W + (size_t)c*HH);
    float acc = bias[c];
#pragma unroll 4
    for (int k4 = 0; k4 < 128; ++k4) {
      float4 wv = wr[k4];
      acc += wv.x*hsh[k4*4] + wv.y*hsh[k4*4+1] + wv.z*hsh[k4*4+2] + wv.w*hsh[k4*4+3];
    }
    out[b*NCLS + c] = acc;
  }
}

extern "C" void kernel_launch(void* const* d_in, const int* in_sizes, int n_in,
                              void* d_out, int out_size, void* d_ws, size_t ws_size,
                              hipStream_t stream) {
  (void)in_sizes; (void)n_in; (void)out_size;
  const float* x    = (const float*)d_in[0];
  const float* mask = (const float*)d_in[1];
  const float* Wih0 = (const float*)d_in[2];
  const float* Whh0 = (const float*)d_in[3];
  const float* bih0 = (const float*)d_in[4];
  const float* bhh0 = (const float*)d_in[5];
  const float* g0   = (const float*)d_in[6];
  const float* be0  = (const float*)d_in[7];
  const float* Wih1 = (const float*)d_in[8];
  const float* Whh1 = (const float*)d_in[9];
  const float* bih1 = (const float*)d_in[10];
  const float* bhh1 = (const float*)d_in[11];
  const float* g1   = (const float*)d_in[12];
  const float* be1  = (const float*)d_in[13];
  const float* fcW  = (const float*)d_in[14];
  const float* fcb  = (const float*)d_in[15];
  float* out = (float*)d_out;

  char* ws = (char*)d_ws;
  size_t off = 0;
  auto alloc = [&](size_t bytes) { size_t o = off; off += (bytes + 255) & ~(size_t)255; return o; };
  f16* G      = (f16*)(ws + alloc((size_t)BT*NG*2));
  f16* HS     = (f16*)(ws + alloc((size_t)BT*HH*2));
  f16* CS     = (f16*)(ws + alloc((size_t)BT*HH*2));
  f16* H0LN   = (f16*)(ws + alloc((size_t)BT*HH*2));
  f16* W16ih0 = (f16*)(ws + alloc((size_t)NG*DD*2));
  f16* W16hh0 = (f16*)(ws + alloc((size_t)NG*HH*2));
  f16* W16ih1 = (f16*)(ws + alloc((size_t)NG*HH*2));
  f16* W16hh1 = (f16*)(ws + alloc((size_t)NG*HH*2));
  float* bias0 = (float*)(ws + alloc(NG*4));
  float* bias1 = (float*)(ws + alloc(NG*4));
  int* counts  = (int*)(ws + alloc(4096));       // counts[s*32], s=0..15 | tailcnt @ +512
  int* tailcnt = counts + 512;
  int* lists   = (int*)(ws + alloc(111168*4));
  int* taillist= (int*)(ws + alloc((size_t)BT*4));
  float* hf    = (float*)(ws + alloc((size_t)BB*HH*4));
  if (ws_size < off) return;

  f16* AX = H0LN;  // x-f16 region, consumed by proj0 before H0LN written

  hipMemsetAsync(counts, 0, 4096, stream);
  prep_weights<<<dim3(512), dim3(256), 0, stream>>>(Wih0, Whh0, Wih1, Whh1, x,
      bih0, bhh0, bih1, bhh1, W16ih0, W16hh0, W16ih1, W16hh1, AX, bias0, bias1);
  build_lists<<<dim3(BB), dim3(512), 0, stream>>>(mask, counts, lists, tailcnt, taillist);

  for (int layer = 0; layer < 2; ++layer) {
    const f16* Wih16 = layer ? W16ih1 : W16ih0;
    const f16* Whh16 = layer ? W16hh1 : W16hh0;
    const float* bias = layer ? bias1 : bias0;
    const f16* Ain = layer ? H0LN : AX;
    int K = layer ? HH : DD;
    proj_gemm<<<dim3((BT/128)*(NG/128)), dim3(256), 0, stream>>>(Ain, Wih16, bias, G, K);
    lstm_step0<<<dim3(BT/4), dim3(512), 0, stream>>>(G, HS, CS, mask, counts, lists);
    for (int s = 1; s < 5; ++s)
      lstm_step<<<dim3(512), dim3(512), 0, stream>>>(Whh16, G, HS, CS, mask, counts, lists, s);
    for (int s = 5; s < MAXS; ++s)
      lstm_step_thin<<<dim3(256), dim3(512), 0, stream>>>(Whh16, G, HS, CS, mask, counts, lists, s);
    lstm_tail<<<dim3(BB), dim3(512), 0, stream>>>(Whh16, G, HS, CS, mask, tailcnt, taillist);
    if (layer == 0)
      ln_relu<<<dim3(BT/8), dim3(512), 0, stream>>>(HS, g0, be0, H0LN);
  }

  ln_last<<<dim3(BB), dim3(512), 0, stream>>>(HS, g1, be1, hf);
  fc_kernel<<<dim3(4, BB), dim3(256), 0, stream>>>(hf, fcW, fcb, out);
}

// Round 7
// 804.002 us; speedup vs baseline: 3.5309x; 1.0514x over previous
//
#include <hip/hip_runtime.h>
#include <stdint.h>

#define BB 64
#define TT 512
#define DD 256
#define HH 512
#define NG 2048
#define BT (BB*TT)
#define NCLS 1000
#define MAXS 16

typedef _Float16 f16;
typedef _Float16 f16x2 __attribute__((ext_vector_type(2)));
typedef _Float16 f16x4 __attribute__((ext_vector_type(4)));
typedef _Float16 f16x8 __attribute__((ext_vector_type(8)));
typedef float f32x4 __attribute__((ext_vector_type(4)));

// bucket list offsets: OFF[s] = 64 * sum_{s'<s} ceil(512/(s'+1)); capacity 111168
__device__ const int d_OFF[MAXS] = {0,32768,49152,60096,68288,74880,80384,85120,
                                    89216,92864,96192,99200,101952,104512,106880,109120};

__device__ __forceinline__ float sigf(float x) { return 1.0f / (1.0f + __expf(-x)); }
__device__ __forceinline__ float tanh_(float x) {
  float e = __expf(-2.0f * fabsf(x));
  float r = (1.0f - e) / (1.0f + e);
  return copysignf(r, x);
}
__device__ __forceinline__ f32x4 mfma16(f16x8 a, f16x8 b, f32x4 c) {
  return __builtin_amdgcn_mfma_f32_16x16x32_f16(a, b, c, 0, 0, 0);
}
__device__ __forceinline__ void gload16(const void* g, void* l) {
  __builtin_amdgcn_global_load_lds((const __attribute__((address_space(1))) void*)g,
                                   (__attribute__((address_space(3))) void*)l, 16, 0, 0);
}

// ---------------- fused: weight casts + bias adds + x cast (one launch) ----------------
#define C0 (NG*DD/4)
#define C1 (C0 + NG*HH/4)
#define C2 (C1 + NG*HH/4)
#define C3 (C2 + NG*HH/4)
#define CX (C3 + BT*DD/4)
__global__ __launch_bounds__(256) void prep_weights(
    const float* __restrict__ Wih0, const float* __restrict__ Whh0,
    const float* __restrict__ Wih1, const float* __restrict__ Whh1,
    const float* __restrict__ x,
    const float* __restrict__ bih0, const float* __restrict__ bhh0,
    const float* __restrict__ bih1, const float* __restrict__ bhh1,
    f16* __restrict__ W16ih0, f16* __restrict__ W16hh0,
    f16* __restrict__ W16ih1, f16* __restrict__ W16hh1,
    f16* __restrict__ AX,
    float* __restrict__ bias0, float* __restrict__ bias1) {
  int gi = blockIdx.x * 256 + threadIdx.x;
  for (int i = gi; i < CX; i += gridDim.x * 256) {
    const float* s; f16* d; int o;
    if (i < C0)      { s = Wih0; d = W16ih0; o = i; }
    else if (i < C1) { s = Whh0; d = W16hh0; o = i - C0; }
    else if (i < C2) { s = Wih1; d = W16ih1; o = i - C1; }
    else if (i < C3) { s = Whh1; d = W16hh1; o = i - C2; }
    else             { s = x;    d = AX;     o = i - C3; }
    float4 v = ((const float4*)s)[o];
    f16x4 h = { (f16)v.x, (f16)v.y, (f16)v.z, (f16)v.w };
    ((f16x4*)d)[o] = h;
  }
  if (gi < NG/2) {
    int j = gi * 2;
    bias0[j]   = bih0[j]   + bhh0[j];
    bias0[j+1] = bih0[j+1] + bhh0[j+1];
    bias1[j]   = bih1[j]   + bhh1[j];
    bias1[j+1] = bih1[j+1] + bhh1[j+1];
  }
}

// ---------------- segment bucket lists + selm (run0 -> mask, else -1) ----------------
__global__ __launch_bounds__(512) void build_lists(const float* __restrict__ mask,
    int* __restrict__ counts, int* __restrict__ lists,
    int* __restrict__ tailcnt, int* __restrict__ taillist,
    float* __restrict__ selm) {
  int b = blockIdx.x, t = threadIdx.x;
  __shared__ float sm[512];
  __shared__ int lcnt[MAXS], lbase[MAXS];
  sm[t] = mask[b*TT + t];
  if (t < MAXS) lcnt[t] = 0;
  __syncthreads();
  int run = 0;
  for (int j = 1; j <= MAXS; ++j) {
    if (t - j < 0) break;
    if (sm[t - j] != 0.0f) run++; else break;
  }
  selm[b*TT + t] = (run == 0) ? sm[t] : -1.0f;
  bool tail = (run >= MAXS);
  int slot = -1;
  if (!tail && run > 0) slot = atomicAdd(&lcnt[run], 1);   // run0 handled in proj_act
  __syncthreads();
  if (t < MAXS) lbase[t] = atomicAdd(&counts[t*32], lcnt[t]);
  __syncthreads();
  if (!tail && run > 0) lists[d_OFF[run] + lbase[run] + slot] = b*TT + t;
  // ordered (by t) per-batch list of tail positions via block scan
  unsigned long long bal = __ballot(tail);
  int lane = t & 63, w = t >> 6;
  int wpre = __popcll(bal & ((1ull << lane) - 1ull));
  __shared__ int wsum[8];
  if (lane == 0) wsum[w] = __popcll(bal);
  __syncthreads();
  int base = 0;
  for (int i = 0; i < w; ++i) base += wsum[i];
  if (tail) taillist[b*TT + base + wpre] = t;
  if (t == 0) {
    int tot = 0;
    for (int i = 0; i < 8; ++i) tot += wsum[i];
    tailcnt[b] = tot;
  }
}

// ---------------- fused projection GEMM + inline step0 ----------------
// tile: 128 rows x (64 j x 4 gates); 8 waves (2 row-grp x 4 j-grp); gate-aligned so the
// epilogue can run the LSTM pointwise for run-0 rows (h_prev=c_prev=0) and skip their G writes.
__global__ __launch_bounds__(512) void proj_act(const f16* __restrict__ A,
    const f16* __restrict__ W, const float* __restrict__ bias,
    f16* __restrict__ G, f16* __restrict__ HS, f16* __restrict__ CS,
    const float* __restrict__ selm, int K) {
  __shared__ __align__(16) f16 smem[128*64 + 256*64];   // As | Bs ; reused as padded stage
  f16* As = smem;
  f16* Bs = smem + 128*64;
  __shared__ float sel[128];
  const int nwg = gridDim.x;                  // 2048, divisible by 8
  const int cpx = nwg >> 3;
  const int swz = (blockIdx.x & 7) * cpx + (blockIdx.x >> 3);
  const int m0 = (swz >> 3) * 128;
  const int j0 = (swz & 7) * 64;
  const int tid = threadIdx.x;
  const int lane = tid & 63;
  const int w = tid >> 6;
  if (tid < 128) sel[tid] = selm[m0 + tid];

  const f16* asrc[2];
#pragma unroll
  for (int p = 0; p < 2; ++p) {
    int cid = tid + p*512;
    int r = cid >> 3, c = cid & 7;
    int cs = c ^ (r & 7);
    asrc[p] = A + (size_t)(m0 + r)*K + cs*8;
  }
  const f16* bsrc[4];
#pragma unroll
  for (int p = 0; p < 4; ++p) {
    int cid = tid + p*512;
    int grow = cid >> 3, c = cid & 7;
    int cs = c ^ (grow & 7);
    int wrow = (grow >> 6)*512 + j0 + (grow & 63);
    bsrc[p] = W + (size_t)wrow*K + cs*8;
  }

  const int rg = w >> 2;
  const int jg = w & 3;
  const int cl = lane & 15;
  const int kq = lane >> 4;
  f32x4 acc[4][4] = {};                       // [row-frag][gate]

  for (int k0 = 0; k0 < K; k0 += 64) {
#pragma unroll
    for (int p = 0; p < 2; ++p)
      gload16(asrc[p] + k0, As + (tid + p*512)*8);
#pragma unroll
    for (int p = 0; p < 4; ++p)
      gload16(bsrc[p] + k0, Bs + (tid + p*512)*8);
    __syncthreads();
#pragma unroll
    for (int ks = 0; ks < 2; ++ks) {
      int kc = ks*4 + kq;
      f16x8 af[4], bf[4];
#pragma unroll
      for (int mi = 0; mi < 4; ++mi) {
        int row = rg*64 + mi*16 + cl;
        af[mi] = *(const f16x8*)(As + row*64 + ((kc ^ (row & 7))*8));
      }
#pragma unroll
      for (int g = 0; g < 4; ++g) {
        int brow = g*64 + jg*16 + cl;
        bf[g] = *(const f16x8*)(Bs + brow*64 + ((kc ^ (brow & 7))*8));
      }
#pragma unroll
      for (int mi = 0; mi < 4; ++mi)
#pragma unroll
        for (int g = 0; g < 4; ++g)
          acc[mi][g] = mfma16(af[mi], bf[g], acc[mi][g]);
    }
    __syncthreads();
  }

  // add bias (per thread: fixed j, 4 gates)
  const int j = j0 + jg*16 + cl;
#pragma unroll
  for (int g = 0; g < 4; ++g) {
    float bb = bias[g*512 + j];
#pragma unroll
    for (int mi = 0; mi < 4; ++mi)
#pragma unroll
      for (int r = 0; r < 4; ++r)
        acc[mi][g][r] += bb;
  }

  // padded LDS restage (2 halves of 64 rows), vectorized epilogue
  f16* stg = smem;                            // [64][264] f16 = 33.8KB <= 48KB
#pragma unroll
  for (int half = 0; half < 2; ++half) {
    if (rg == half) {
#pragma unroll
      for (int mi = 0; mi < 4; ++mi)
#pragma unroll
        for (int g = 0; g < 4; ++g)
#pragma unroll
          for (int r = 0; r < 4; ++r) {
            int row_l = mi*16 + kq*4 + r;
            stg[row_l*264 + g*64 + jg*16 + cl] = (f16)acc[mi][g][r];
          }
    }
    __syncthreads();
    {
      int row_l = tid >> 3, sl = tid & 7;
      int slot = half*64 + row_l;
      int row = m0 + slot;
      int jj = j0 + sl*8;
      f16x8 vi = *(const f16x8*)(stg + row_l*264 +        sl*8);
      f16x8 vf = *(const f16x8*)(stg + row_l*264 +  64 + sl*8);
      f16x8 vg = *(const f16x8*)(stg + row_l*264 + 128 + sl*8);
      f16x8 vo = *(const f16x8*)(stg + row_l*264 + 192 + sl*8);
      float sm = sel[slot];
      if (sm >= 0.0f) {
        f16x8 hv, cv;
#pragma unroll
        for (int e = 0; e < 8; ++e) {
          float c = sigf((float)vi[e]) * tanh_((float)vg[e]);
          float h = sigf((float)vo[e]) * tanh_(c);
          hv[e] = (f16)(h*sm); cv[e] = (f16)(c*sm);
        }
        *(f16x8*)(HS + (size_t)row*HH + jj) = hv;
        *(f16x8*)(CS + (size_t)row*HH + jj) = cv;
      } else {
        *(f16x8*)(G + (size_t)row*NG +        jj) = vi;
        *(f16x8*)(G + (size_t)row*NG +  512 + jj) = vf;
        *(f16x8*)(G + (size_t)row*NG + 1024 + jj) = vg;
        *(f16x8*)(G + (size_t)row*NG + 1536 + jj) = vo;
      }
    }
    __syncthreads();
  }
}

// ---------------- bucket s (1..4): tiled MFMA step, vectorized restaged epilogue ----------------
__global__ __launch_bounds__(512) void lstm_step(const f16* __restrict__ Wh,
    const f16* __restrict__ G, f16* __restrict__ HS, f16* __restrict__ CS,
    const float* __restrict__ mask, const int* __restrict__ counts,
    const int* __restrict__ lists, int s) {
  const int cnt = counts[s*32];
  if (cnt == 0) return;
  const int units = ((cnt + 127) >> 7) * 8;
  const int* lst = lists + d_OFF[s];
  const int tid = threadIdx.x;
  const int lane = tid & 63;
  const int w = tid >> 6;
  __shared__ __align__(16) f16 smem[128*64 + 256*64];
  f16* As = smem;
  f16* Bs = smem + 128*64;
  __shared__ int ridx[128];
  __shared__ float rmk[128];
  const int rg = w >> 2;
  const int jg = w & 3;
  const int cl = lane & 15;
  const int kq = lane >> 4;

  for (int u = blockIdx.x; u < units; u += gridDim.x) {
    const int mbase = (u >> 3) * 128;
    const int j0 = (u & 7) * 64;
    if (tid < 128) {
      int i = mbase + tid;
      int r = (i < cnt) ? lst[i] : -1;
      ridx[tid] = r;
      rmk[tid] = (r >= 0) ? mask[r] : 0.0f;
    }
    __syncthreads();

    const f16* asrc[2];
#pragma unroll
    for (int p = 0; p < 2; ++p) {
      int cid = tid + p*512;
      int r = cid >> 3, c = cid & 7;
      int cs = c ^ (r & 7);
      int rr = ridx[r];
      int sr = (rr >= 1 ? rr : 1) - 1;
      asrc[p] = HS + (size_t)sr*HH + cs*8;
    }
    const f16* bsrc[4];
#pragma unroll
    for (int p = 0; p < 4; ++p) {
      int cid = tid + p*512;
      int grow = cid >> 3, c = cid & 7;
      int cs = c ^ (grow & 7);
      int wrow = (grow >> 6)*512 + j0 + (grow & 63);
      bsrc[p] = Wh + (size_t)wrow*HH + cs*8;
    }

    f32x4 acc[4][4] = {};
    for (int k0 = 0; k0 < HH; k0 += 64) {
#pragma unroll
      for (int p = 0; p < 2; ++p)
        gload16(asrc[p] + k0, As + (tid + p*512)*8);
#pragma unroll
      for (int p = 0; p < 4; ++p)
        gload16(bsrc[p] + k0, Bs + (tid + p*512)*8);
      __syncthreads();
#pragma unroll
      for (int ks = 0; ks < 2; ++ks) {
        int kc = ks*4 + kq;
        f16x8 af[4], bf[4];
#pragma unroll
        for (int mi = 0; mi < 4; ++mi) {
          int row = rg*64 + mi*16 + cl;
          af[mi] = *(const f16x8*)(As + row*64 + ((kc ^ (row & 7))*8));
        }
#pragma unroll
        for (int g = 0; g < 4; ++g) {
          int brow = g*64 + jg*16 + cl;
          bf[g] = *(const f16x8*)(Bs + brow*64 + ((kc ^ (brow & 7))*8));
        }
#pragma unroll
        for (int mi = 0; mi < 4; ++mi)
#pragma unroll
          for (int g = 0; g < 4; ++g)
            acc[mi][g] = mfma16(af[mi], bf[g], acc[mi][g]);
      }
      __syncthreads();
    }

    // padded LDS restage epilogue (vectorized G/CS/HS access)
    f16* stg = smem;
#pragma unroll
    for (int half = 0; half < 2; ++half) {
      if (rg == half) {
#pragma unroll
        for (int mi = 0; mi < 4; ++mi)
#pragma unroll
          for (int g = 0; g < 4; ++g)
#pragma unroll
            for (int r = 0; r < 4; ++r) {
              int row_l = mi*16 + kq*4 + r;
              stg[row_l*264 + g*64 + jg*16 + cl] = (f16)acc[mi][g][r];
            }
      }
      __syncthreads();
      {
        int row_l = tid >> 3, sl = tid & 7;
        int slot = half*64 + row_l;
        int row = ridx[slot];
        if (row >= 0) {
          int jj = j0 + sl*8;
          f16x8 ai = *(const f16x8*)(stg + row_l*264 +        sl*8);
          f16x8 af2 = *(const f16x8*)(stg + row_l*264 +  64 + sl*8);
          f16x8 ag = *(const f16x8*)(stg + row_l*264 + 128 + sl*8);
          f16x8 ao = *(const f16x8*)(stg + row_l*264 + 192 + sl*8);
          f16x8 Gi = *(const f16x8*)(G + (size_t)row*NG +        jj);
          f16x8 Gf = *(const f16x8*)(G + (size_t)row*NG +  512 + jj);
          f16x8 Gg = *(const f16x8*)(G + (size_t)row*NG + 1024 + jj);
          f16x8 Go = *(const f16x8*)(G + (size_t)row*NG + 1536 + jj);
          f16x8 cp = *(const f16x8*)(CS + (size_t)(row - 1)*HH + jj);
          float m = rmk[slot];
          f16x8 hv, cv;
#pragma unroll
          for (int e = 0; e < 8; ++e) {
            float gi = (float)ai[e] + (float)Gi[e];
            float gf = (float)af2[e] + (float)Gf[e];
            float gg = (float)ag[e] + (float)Gg[e];
            float go = (float)ao[e] + (float)Go[e];
            float c = sigf(gf)*(float)cp[e] + sigf(gi)*tanh_(gg);
            float h = sigf(go)*tanh_(c);
            hv[e] = (f16)(h*m); cv[e] = (f16)(c*m);
          }
          *(f16x8*)(HS + (size_t)row*HH + jj) = hv;
          *(f16x8*)(CS + (size_t)row*HH + jj) = cv;
        }
      }
      __syncthreads();
    }
  }
}

// ---------------- bucket s (5..15): THIN tiled MFMA step (small counts) ----------------
__global__ __launch_bounds__(512) void lstm_step_thin(const f16* __restrict__ Wh,
    const f16* __restrict__ G, f16* __restrict__ HS, f16* __restrict__ CS,
    const float* __restrict__ mask, const int* __restrict__ counts,
    const int* __restrict__ lists, int s) {
  const int cnt = counts[s*32];
  if (cnt == 0) return;
  const int units = ((cnt + 127) >> 7) * 32;
  const int* lst = lists + d_OFF[s];
  const int tid = threadIdx.x;
  const int lane = tid & 63;
  const int w = tid >> 6;
  __shared__ __align__(16) f16 As[128*64];   // 16KB
  __shared__ __align__(16) f16 Bs[64*64];    // 8KB: grow = gate*16 + jj
  __shared__ int ridx[128];
  __shared__ float rmk[128];
  const int cl = lane & 15;
  const int kq = lane >> 4;
  const int rbase = w * 16;

  for (int u = blockIdx.x; u < units; u += gridDim.x) {
    const int mbase = (u >> 5) * 128;
    const int j0 = (u & 31) * 16;
    if (tid < 128) {
      int i = mbase + tid;
      int r = (i < cnt) ? lst[i] : -1;
      ridx[tid] = r;
      rmk[tid] = (r >= 0) ? mask[r] : 0.0f;
    }
    __syncthreads();

    const f16* asrc[2];
#pragma unroll
    for (int p = 0; p < 2; ++p) {
      int cid = tid + p*512;
      int r = cid >> 3, c = cid & 7;
      int cs = c ^ (r & 7);
      int rr = ridx[r];
      int sr = (rr >= 1 ? rr : 1) - 1;
      asrc[p] = HS + (size_t)sr*HH + cs*8;
    }
    const f16* bsrc;
    {
      int grow = tid >> 3, c = tid & 7;
      int cs = c ^ (grow & 7);
      int wrow = (grow >> 4)*512 + j0 + (grow & 15);
      bsrc = Wh + (size_t)wrow*HH + cs*8;
    }

    f32x4 acc[4] = {};
    for (int k0 = 0; k0 < HH; k0 += 64) {
#pragma unroll
      for (int p = 0; p < 2; ++p)
        gload16(asrc[p] + k0, As + (tid + p*512)*8);
      gload16(bsrc + k0, Bs + tid*8);
      __syncthreads();
#pragma unroll
      for (int ks = 0; ks < 2; ++ks) {
        int kc = ks*4 + kq;
        int arow = rbase + cl;
        f16x8 af = *(const f16x8*)(As + arow*64 + ((kc ^ (arow & 7))*8));
        f16x8 bf[4];
#pragma unroll
        for (int g = 0; g < 4; ++g) {
          int brow = g*16 + cl;
          bf[g] = *(const f16x8*)(Bs + brow*64 + ((kc ^ (brow & 7))*8));
        }
#pragma unroll
        for (int g = 0; g < 4; ++g)
          acc[g] = mfma16(af, bf[g], acc[g]);
      }
      __syncthreads();
    }

    const int j = j0 + cl;
#pragma unroll
    for (int r = 0; r < 4; ++r) {
      int slot = rbase + kq*4 + r;
      int row = ridx[slot];
      if (row >= 0) {
        size_t gb = (size_t)row * NG;
        float gi = acc[0][r] + (float)G[gb + j];
        float gf = acc[1][r] + (float)G[gb + 512 + j];
        float gg = acc[2][r] + (float)G[gb + 1024 + j];
        float go = acc[3][r] + (float)G[gb + 1536 + j];
        float cp = (float)CS[(size_t)(row - 1)*HH + j];
        float c = sigf(gf)*cp + sigf(gi)*tanh_(gg);
        float h = sigf(go)*tanh_(c);
        float m = rmk[slot];
        HS[(size_t)row*HH + j] = (f16)(h*m);
        CS[(size_t)row*HH + j] = (f16)(c*m);
      }
    }
    __syncthreads();
  }
}

// ---------------- tail: run >= 16, sequential per batch (rare; coalesced matvec) ----------------
__global__ __launch_bounds__(512) void lstm_tail(const f16* __restrict__ Wh,
    const f16* __restrict__ G, f16* __restrict__ HS, f16* __restrict__ CS,
    const float* __restrict__ mask, const int* __restrict__ tailcnt,
    const int* __restrict__ taillist) {
  int b = blockIdx.x;
  int n = tailcnt[b];
  if (n == 0) return;
  int tid = threadIdx.x, lane = tid & 63, w = tid >> 6;
  const int rl = lane >> 3;
  const int kb = (lane & 7) * 8;
  __shared__ __align__(16) f16 hsh[HH];
  __shared__ float gsh[NG];
  for (int i = 0; i < n; ++i) {
    int t = taillist[b*TT + i];
    size_t row = (size_t)b*TT + t;
    if (tid < 256)
      ((uint32_t*)hsh)[tid] = ((const uint32_t*)(HS + (row - 1)*HH))[tid];
    __syncthreads();
    f16x8 hreg[8];
#pragma unroll
    for (int kk = 0; kk < 8; ++kk)
      hreg[kk] = *(const f16x8*)(hsh + kb + kk*64);
#pragma unroll 2
    for (int batch = 0; batch < 32; ++batch) {
      int o = (w*32 + batch)*8 + rl;
      const f16* wrow = Wh + (size_t)o*HH + kb;
      float p = 0.0f;
#pragma unroll
      for (int kk = 0; kk < 8; ++kk) {
        f16x8 wv = *(const f16x8*)(wrow + kk*64);
        f16x2 w0 = {wv[0], wv[1]}, w1 = {wv[2], wv[3]}, w2 = {wv[4], wv[5]}, w3 = {wv[6], wv[7]};
        f16x2 h0 = {hreg[kk][0], hreg[kk][1]}, h1 = {hreg[kk][2], hreg[kk][3]},
              h2 = {hreg[kk][4], hreg[kk][5]}, h3 = {hreg[kk][6], hreg[kk][7]};
        p = __builtin_amdgcn_fdot2(w0, h0, p, false);
        p = __builtin_amdgcn_fdot2(w1, h1, p, false);
        p = __builtin_amdgcn_fdot2(w2, h2, p, false);
        p = __builtin_amdgcn_fdot2(w3, h3, p, false);
      }
      p += __shfl_xor(p, 1);
      p += __shfl_xor(p, 2);
      p += __shfl_xor(p, 4);
      if ((lane & 7) == 0) gsh[o] = p + (float)G[row*NG + o];
    }
    __syncthreads();
    {
      float cp = (float)CS[(row - 1)*HH + tid];
      float c = sigf(gsh[512 + tid])*cp + sigf(gsh[tid])*tanh_(gsh[1024 + tid]);
      float h = sigf(gsh[1536 + tid])*tanh_(c);
      float m = mask[row];
      HS[row*HH + tid] = (f16)(h*m);
      CS[row*HH + tid] = (f16)(c*m);
    }
    __syncthreads();
  }
}

// ---------------- relu + layernorm, wave-per-row ----------------
__global__ __launch_bounds__(512) void ln_relu(const f16* __restrict__ in,
    const float* __restrict__ g, const float* __restrict__ be,
    f16* __restrict__ out) {
  int lane = threadIdx.x & 63, w = threadIdx.x >> 6;
  int row = blockIdx.x * 8 + w;
  f16x8 hv = *(const f16x8*)(in + (size_t)row*HH + lane*8);
  float xv[8]; float s1 = 0.f, s2 = 0.f;
#pragma unroll
  for (int e = 0; e < 8; ++e) { float x = fmaxf((float)hv[e], 0.f); xv[e] = x; s1 += x; s2 += x*x; }
#pragma unroll
  for (int o = 1; o < 64; o <<= 1) { s1 += __shfl_xor(s1, o); s2 += __shfl_xor(s2, o); }
  float mu = s1 * (1.0f/512.0f);
  float var = s2 * (1.0f/512.0f) - mu*mu;
  float rs = rsqrtf(var + 1e-5f);
  f16x8 ov;
#pragma unroll
  for (int e = 0; e < 8; ++e) ov[e] = (f16)((xv[e] - mu)*rs*g[lane*8+e] + be[lane*8+e]);
  *(f16x8*)(out + (size_t)row*HH + lane*8) = ov;
}

// layernorm of the final (t=T-1) hidden state, f32 output
__global__ __launch_bounds__(512) void ln_last(const f16* __restrict__ HS,
    const float* __restrict__ g, const float* __restrict__ be, float* __restrict__ out) {
  int b = blockIdx.x;
  int j = threadIdx.x;
  float x = fmaxf((float)HS[((size_t)b*TT + (TT-1))*HH + j], 0.0f);
  float s1 = x, s2 = x*x;
  for (int o = 32; o > 0; o >>= 1) { s1 += __shfl_down(s1, o); s2 += __shfl_down(s2, o); }
  __shared__ float a1[8], a2[8];
  int w = j >> 6;
  if ((j & 63) == 0) { a1[w] = s1; a2[w] = s2; }
  __syncthreads();
  if (j == 0) {
    float t1 = 0.f, t2 = 0.f;
    for (int i = 0; i < 8; ++i) { t1 += a1[i]; t2 += a2[i]; }
    a1[0] = t1; a2[0] = t2;
  }
  __syncthreads();
  float mu = a1[0] * (1.0f/512.0f);
  float var = a2[0] * (1.0f/512.0f) - mu*mu;
  float y = (x - mu) * rsqrtf(var + 1e-5f) * g[j] + be[j];
  out[b*HH + j] = y;
}

// ---------------- final classifier: out[64][1000] = hf @ fcW^T + fcb ----------------
__global__ __launch_bounds__(256) void fc_kernel(const float* __restrict__ hf,
    const float* __restrict__ W, const float* __restrict__ bias, float* __restrict__ out) {
  int b = blockIdx.y;
  int c = blockIdx.x * 256 + threadIdx.x;
  __shared__ float hsh[512];
  hsh[threadIdx.x] = hf[b*HH + threadIdx.x];
  hsh[threadIdx.x + 256] = hf[b*HH + 256 + threadIdx.x];
  __syncthreads();
  if (c < NCLS) {
    const float4* wr = (const float4*)(W + (size_t)c*HH);
    float acc = bias[c];
#pragma unroll 4
    for (int k4 = 0; k4 < 128; ++k4) {
      float4 wv = wr[k4];
      acc += wv.x*hsh[k4*4] + wv.y*hsh[k4*4+1] + wv.z*hsh[k4*4+2] + wv.w*hsh[k4*4+3];
    }
    out[b*NCLS + c] = acc;
  }
}

extern "C" void kernel_launch(void* const* d_in, const int* in_sizes, int n_in,
                              void* d_out, int out_size, void* d_ws, size_t ws_size,
                              hipStream_t stream) {
  (void)in_sizes; (void)n_in; (void)out_size;
  const float* x    = (const float*)d_in[0];
  const float* mask = (const float*)d_in[1];
  const float* Wih0 = (const float*)d_in[2];
  const float* Whh0 = (const float*)d_in[3];
  const float* bih0 = (const float*)d_in[4];
  const float* bhh0 = (const float*)d_in[5];
  const float* g0   = (const float*)d_in[6];
  const float* be0  = (const float*)d_in[7];
  const float* Wih1 = (const float*)d_in[8];
  const float* Whh1 = (const float*)d_in[9];
  const float* bih1 = (const float*)d_in[10];
  const float* bhh1 = (const float*)d_in[11];
  const float* g1   = (const float*)d_in[12];
  const float* be1  = (const float*)d_in[13];
  const float* fcW  = (const float*)d_in[14];
  const float* fcb  = (const float*)d_in[15];
  float* out = (float*)d_out;

  char* ws = (char*)d_ws;
  size_t off = 0;
  auto alloc = [&](size_t bytes) { size_t o = off; off += (bytes + 255) & ~(size_t)255; return o; };
  f16* G      = (f16*)(ws + alloc((size_t)BT*NG*2));
  f16* HS     = (f16*)(ws + alloc((size_t)BT*HH*2));
  f16* CS     = (f16*)(ws + alloc((size_t)BT*HH*2));
  f16* H0LN   = (f16*)(ws + alloc((size_t)BT*HH*2));
  f16* W16ih0 = (f16*)(ws + alloc((size_t)NG*DD*2));
  f16* W16hh0 = (f16*)(ws + alloc((size_t)NG*HH*2));
  f16* W16ih1 = (f16*)(ws + alloc((size_t)NG*HH*2));
  f16* W16hh1 = (f16*)(ws + alloc((size_t)NG*HH*2));
  float* bias0 = (float*)(ws + alloc(NG*4));
  float* bias1 = (float*)(ws + alloc(NG*4));
  int* counts  = (int*)(ws + alloc(4096));       // counts[s*32], s=0..15 | tailcnt @ +512
  int* tailcnt = counts + 512;
  int* lists   = (int*)(ws + alloc(111168*4));
  int* taillist= (int*)(ws + alloc((size_t)BT*4));
  float* selm  = (float*)(ws + alloc((size_t)BT*4));
  float* hf    = (float*)(ws + alloc((size_t)BB*HH*4));
  if (ws_size < off) return;

  f16* AX = H0LN;  // x-f16 region, consumed by proj_act L0 before H0LN written

  hipMemsetAsync(counts, 0, 4096, stream);
  prep_weights<<<dim3(512), dim3(256), 0, stream>>>(Wih0, Whh0, Wih1, Whh1, x,
      bih0, bhh0, bih1, bhh1, W16ih0, W16hh0, W16ih1, W16hh1, AX, bias0, bias1);
  build_lists<<<dim3(BB), dim3(512), 0, stream>>>(mask, counts, lists, tailcnt, taillist, selm);

  for (int layer = 0; layer < 2; ++layer) {
    const f16* Wih16 = layer ? W16ih1 : W16ih0;
    const f16* Whh16 = layer ? W16hh1 : W16hh0;
    const float* bias = layer ? bias1 : bias0;
    const f16* Ain = layer ? H0LN : AX;
    int K = layer ? HH : DD;
    proj_act<<<dim3((BT/128)*8), dim3(512), 0, stream>>>(Ain, Wih16, bias, G, HS, CS, selm, K);
    for (int s = 1; s < 5; ++s)
      lstm_step<<<dim3(512), dim3(512), 0, stream>>>(Whh16, G, HS, CS, mask, counts, lists, s);
    for (int s = 5; s < MAXS; ++s)
      lstm_step_thin<<<dim3(256), dim3(512), 0, stream>>>(Whh16, G, HS, CS, mask, counts, lists, s);
    lstm_tail<<<dim3(BB), dim3(512), 0, stream>>>(Whh16, G, HS, CS, mask, tailcnt, taillist);
    if (layer == 0)
      ln_relu<<<dim3(BT/8), dim3(512), 0, stream>>>(HS, g0, be0, H0LN);
  }

  ln_last<<<dim3(BB), dim3(512), 0, stream>>>(HS, g1, be1, hf);
  fc_kernel<<<dim3(4, BB), dim3(256), 0, stream>>>(hf, fcW, fcb, out);
}